// Round 11
// baseline (693.483 us; speedup 1.0000x reference)
//
#include <hip/hip_runtime.h>
#include <hip/hip_cooperative_groups.h>
namespace cg = cooperative_groups;

__device__ __forceinline__ float siluf(float x){ return x / (1.f + __expf(-x)); }
__device__ __forceinline__ float softplusf(float x){
    return fmaxf(x, 0.f) + __logf(1.f + __expf(-fabsf(x)));
}
#if __has_builtin(__builtin_amdgcn_exp2f)
__device__ __forceinline__ float fexp2(float x){ return __builtin_amdgcn_exp2f(x); }
#else
__device__ __forceinline__ float fexp2(float x){ return exp2f(x); }
#endif

// ==== cooperative spa kernel: inproj+conv -> xproj -> p1 -> p2a -> p2c ->
//      p3 replay + gate + outproj + GN partials. 1024 blocks, all resident.
// LDS (floats): SXC 2048 | SZ 2048 | SBM 256 | SCM 256 | DTR 64 | PGS 32 |
//               YPL 4096 (SXE 11x68 aliases YPL during phase 0)  = 8800
#define SXC_  0
#define SZ_   2048
#define SBM_  4096
#define SCM_  4352
#define DTR_  4608
#define PGS_  4672
#define YPL_  4704
#define SXE_  4704

__global__ void __launch_bounds__(256, 4) k_spa_coop(
        const float* __restrict__ x,
        const float* __restrict__ in_w, const float* __restrict__ cw, const float* __restrict__ cb,
        const float* __restrict__ xpw, const float* __restrict__ dtw, const float* __restrict__ dtb,
        const float* __restrict__ A_log, const float* __restrict__ Dv, const float* __restrict__ ow,
        float* __restrict__ Pb, float* __restrict__ Qb, float* __restrict__ Ps, float* __restrict__ Qs,
        float* __restrict__ Hs, float* __restrict__ ys, float* __restrict__ sp)
{
    __shared__ float smem[8800];
    cg::grid_group grid = cg::this_grid();
    const int tid = threadIdx.x;
    const int ch  = blockIdx.x;          // 16-token chunk, 0..1023

    // ---- phase 0: in_proj + causal conv + SiLU (2 passes of 8 tokens) ----
    {
        float wr[64];
        const float4* w4 = (const float4*)(in_w + tid*64);
        #pragma unroll
        for (int k = 0; k < 16; ++k){
            float4 v = w4[k];
            wr[4*k]=v.x; wr[4*k+1]=v.y; wr[4*k+2]=v.z; wr[4*k+3]=v.w;
        }
        float cw0=0.f,cw1=0.f,cw2=0.f,cw3=0.f,cbd=0.f;
        if (tid < 128){
            cw0 = cw[tid*4+0]; cw1 = cw[tid*4+1];
            cw2 = cw[tid*4+2]; cw3 = cw[tid*4+3];
            cbd = cb[tid];
        }
        for (int pass = 0; pass < 2; ++pass){
            int l0 = ch*16 + pass*8;
            #pragma unroll
            for (int it = 0; it < 3; ++it){
                int idx = it*256 + tid;
                if (idx < 704){
                    int r = idx >> 6, c = idx & 63;
                    int p = l0 - 3 + r;
                    float v = 0.f;
                    if (p >= 0) v = x[(size_t)(p >> 12)*262144 + c*4096 + (p & 4095)];
                    smem[SXE_ + r*68 + c] = v;
                }
            }
            __syncthreads();
            if (tid < 128){
                float acc[11];
                #pragma unroll
                for (int r = 0; r < 11; ++r) acc[r] = 0.f;
                #pragma unroll
                for (int k = 0; k < 16; ++k){
                    #pragma unroll
                    for (int r = 0; r < 11; ++r){
                        float4 v = *(const float4*)&smem[SXE_ + r*68 + 4*k];
                        acc[r] = fmaf(v.x, wr[4*k],   acc[r]);
                        acc[r] = fmaf(v.y, wr[4*k+1], acc[r]);
                        acc[r] = fmaf(v.z, wr[4*k+2], acc[r]);
                        acc[r] = fmaf(v.w, wr[4*k+3], acc[r]);
                    }
                }
                #pragma unroll
                for (int r = 0; r < 8; ++r){
                    float a = fmaf(cw0, acc[r],   cbd);
                    a = fmaf(cw1, acc[r+1], a);
                    a = fmaf(cw2, acc[r+2], a);
                    a = fmaf(cw3, acc[r+3], a);
                    smem[SXC_ + (pass*8+r)*128 + tid] = siluf(a);
                }
            } else {
                float acc[8];
                #pragma unroll
                for (int r = 0; r < 8; ++r) acc[r] = 0.f;
                #pragma unroll
                for (int k = 0; k < 16; ++k){
                    #pragma unroll
                    for (int r = 0; r < 8; ++r){
                        float4 v = *(const float4*)&smem[SXE_ + (r+3)*68 + 4*k];
                        acc[r] = fmaf(v.x, wr[4*k],   acc[r]);
                        acc[r] = fmaf(v.y, wr[4*k+1], acc[r]);
                        acc[r] = fmaf(v.z, wr[4*k+2], acc[r]);
                        acc[r] = fmaf(v.w, wr[4*k+3], acc[r]);
                    }
                }
                #pragma unroll
                for (int r = 0; r < 8; ++r)
                    smem[SZ_ + (pass*8+r)*128 + (tid-128)] = acc[r];
            }
            __syncthreads();
        }
    }

    // ---- phase 1: x_proj (dt + B + C), computed ONCE for p1 and p3 -------
    {
        int j = tid & 63, tg = tid >> 6;
        if (j < 36){
            const float4* w4  = (const float4*)(xpw + j*128);
            const float4* xc4 = (const float4*)(smem + SXC_) + tg*128;  // 4 tokens
            float acc[4];
            #pragma unroll
            for (int r = 0; r < 4; ++r) acc[r] = 0.f;
            #pragma unroll 8
            for (int k = 0; k < 32; ++k){
                float4 w = w4[k];
                #pragma unroll
                for (int r = 0; r < 4; ++r){
                    float4 v = xc4[r*32 + k];
                    acc[r] = fmaf(v.x, w.x, acc[r]);
                    acc[r] = fmaf(v.y, w.y, acc[r]);
                    acc[r] = fmaf(v.z, w.z, acc[r]);
                    acc[r] = fmaf(v.w, w.w, acc[r]);
                }
            }
            if (j < 4){
                #pragma unroll
                for (int r = 0; r < 4; ++r) smem[DTR_ + (tg*4+r)*4 + j] = acc[r];
            } else if (j < 20){
                #pragma unroll
                for (int r = 0; r < 4; ++r) smem[SBM_ + (tg*4+r)*16 + (j-4)] = acc[r];
            } else {
                #pragma unroll
                for (int r = 0; r < 4; ++r) smem[SCM_ + (tg*4+r)*16 + (j-20)] = acc[r];
            }
        }
    }
    __syncthreads();

    // ---- phase 2: p1 chunk summary (P,Q) ---------------------------------
    const int d  = tid & 127;
    const int sh = tid >> 7;
    float A8[8];
    {
        const float4* al4 = (const float4*)(A_log + d*16 + sh*8);
        float4 v0 = al4[0], v1 = al4[1];
        A8[0]=-__expf(v0.x)*1.44269504f; A8[1]=-__expf(v0.y)*1.44269504f;
        A8[2]=-__expf(v0.z)*1.44269504f; A8[3]=-__expf(v0.w)*1.44269504f;
        A8[4]=-__expf(v1.x)*1.44269504f; A8[5]=-__expf(v1.y)*1.44269504f;
        A8[6]=-__expf(v1.z)*1.44269504f; A8[7]=-__expf(v1.w)*1.44269504f;
    }
    float4 dw = *(const float4*)(dtw + d*4);
    float dbd = dtb[d];
    {
        float P[8], Q[8];
        #pragma unroll
        for (int s = 0; s < 8; ++s){ P[s] = 1.f; Q[s] = 0.f; }
        #pragma unroll 4
        for (int i = 0; i < 16; ++i){
            float4 dt4 = *(const float4*)&smem[DTR_ + i*4];
            float dv = dbd;
            dv = fmaf(dt4.x, dw.x, dv);
            dv = fmaf(dt4.y, dw.y, dv);
            dv = fmaf(dt4.z, dw.z, dv);
            dv = fmaf(dt4.w, dw.w, dv);
            float dt = softplusf(dv);
            float db = dt * smem[SXC_ + i*128 + d];
            const float4* bmr = (const float4*)&smem[SBM_ + i*16 + sh*8];
            float4 b0 = bmr[0], b1 = bmr[1];
            float bv[8] = {b0.x,b0.y,b0.z,b0.w,b1.x,b1.y,b1.z,b1.w};
            #pragma unroll
            for (int s = 0; s < 8; ++s){
                float a = fexp2(dt*A8[s]);
                P[s] *= a;
                Q[s] = fmaf(a, Q[s], db*bv[s]);
            }
        }
        float* Pp = Pb + (size_t)ch*2048 + d*16 + sh*8;
        float* Qp = Qb + (size_t)ch*2048 + d*16 + sh*8;
        ((float4*)Pp)[0] = make_float4(P[0],P[1],P[2],P[3]);
        ((float4*)Pp)[1] = make_float4(P[4],P[5],P[6],P[7]);
        ((float4*)Qp)[0] = make_float4(Q[0],Q[1],Q[2],Q[3]);
        ((float4*)Qp)[1] = make_float4(Q[4],Q[5],Q[6],Q[7]);
    }
    __threadfence();
    grid.sync();

    // ---- phase 3: p2a — compose 64 units per super (blocks 0..127) -------
    if (ch < 128){
        int g = ch*256 + tid;
        int sup = g >> 11;
        int lane = g & 2047;
        float P = 1.f, Q = 0.f;
        for (int i = 0; i < 64; i += 8){
            float p[8], q[8];
            #pragma unroll
            for (int u = 0; u < 8; ++u){
                p[u] = Pb[(size_t)(sup*64+i+u)*2048 + lane];
                q[u] = Qb[(size_t)(sup*64+i+u)*2048 + lane];
            }
            #pragma unroll
            for (int u = 0; u < 8; ++u){
                P = p[u]*P;
                Q = fmaf(p[u], Q, q[u]);
            }
        }
        Ps[g] = P; Qs[g] = Q;
    }
    __threadfence();
    grid.sync();

    // ---- phase 4: p2c — unit-level prefix, Hsup inline -------------------
    if (ch < 128){
        int g = ch*256 + tid;
        int sup = g >> 11;
        int lane = g & 2047;
        float h = 0.f;
        for (int u = 0; u < sup; ++u){
            float p = Ps[u*2048 + lane];
            float q = Qs[u*2048 + lane];
            h = fmaf(p, h, q);
        }
        for (int i = 0; i < 64; i += 8){
            float p[8], q[8];
            #pragma unroll
            for (int u = 0; u < 8; ++u){
                p[u] = Pb[(size_t)(sup*64+i+u)*2048 + lane];
                q[u] = Qb[(size_t)(sup*64+i+u)*2048 + lane];
            }
            #pragma unroll
            for (int u = 0; u < 8; ++u){
                Hs[(size_t)(sup*64+i+u)*2048 + lane] = h;
                h = fmaf(p[u], h, q[u]);
            }
        }
    }
    __threadfence();
    grid.sync();

    // ---- phase 5: p3 replay with h0, gate, D-skip, out_proj, GN partials -
    {
        float h[8];
        const float4* h4 = (const float4*)(Hs + (size_t)ch*2048 + d*16 + sh*8);
        float4 h0 = h4[0], h1 = h4[1];
        h[0]=h0.x; h[1]=h0.y; h[2]=h0.z; h[3]=h0.w;
        h[4]=h1.x; h[5]=h1.y; h[6]=h1.z; h[7]=h1.w;
        #pragma unroll 4
        for (int i = 0; i < 16; ++i){
            float4 dt4 = *(const float4*)&smem[DTR_ + i*4];
            float dv = dbd;
            dv = fmaf(dt4.x, dw.x, dv);
            dv = fmaf(dt4.y, dw.y, dv);
            dv = fmaf(dt4.z, dw.z, dv);
            dv = fmaf(dt4.w, dw.w, dv);
            float dt = softplusf(dv);
            float db = dt * smem[SXC_ + i*128 + d];
            const float4* bmr = (const float4*)&smem[SBM_ + i*16 + sh*8];
            const float4* cmr = (const float4*)&smem[SCM_ + i*16 + sh*8];
            float4 b0 = bmr[0], b1 = bmr[1];
            float4 c0 = cmr[0], c1 = cmr[1];
            float bv[8] = {b0.x,b0.y,b0.z,b0.w,b1.x,b1.y,b1.z,b1.w};
            float cv[8] = {c0.x,c0.y,c0.z,c0.w,c1.x,c1.y,c1.z,c1.w};
            float yp = 0.f;
            #pragma unroll
            for (int s = 0; s < 8; ++s){
                float a = fexp2(dt*A8[s]);
                h[s] = fmaf(a, h[s], db*bv[s]);
                yp = fmaf(h[s], cv[s], yp);
            }
            smem[YPL_ + sh*2048 + i*128 + d] = yp;
        }
    }
    __syncthreads();
    #pragma unroll
    for (int it = 0; it < 8; ++it){
        int idx = it*256 + tid;
        float yp = smem[YPL_ + idx] + smem[YPL_ + 2048 + idx];
        float xcd = smem[SXC_ + idx];
        float zv  = smem[SZ_ + idx];
        smem[YPL_ + idx] = (yp + xcd*Dv[idx & 127]) * siluf(zv);
    }
    __syncthreads();
    {
        int c  = tid & 63;
        int kh = (tid >> 6) & 1;
        int rg = tid >> 7;                // 2 row groups x 8 rows
        float wr2[64];
        const float4* w4o = (const float4*)(ow + c*128 + kh*64);
        #pragma unroll
        for (int k = 0; k < 16; ++k){
            float4 v = w4o[k];
            wr2[4*k]=v.x; wr2[4*k+1]=v.y; wr2[4*k+2]=v.z; wr2[4*k+3]=v.w;
        }
        float acc[8];
        #pragma unroll
        for (int r = 0; r < 8; ++r) acc[r] = 0.f;
        const float4* y4 = (const float4*)(smem + YPL_ + rg*8*128 + kh*64);
        #pragma unroll
        for (int k = 0; k < 16; ++k){
            #pragma unroll
            for (int r = 0; r < 8; ++r){
                float4 v = y4[r*32 + k];
                acc[r] = fmaf(v.x, wr2[4*k],   acc[r]);
                acc[r] = fmaf(v.y, wr2[4*k+1], acc[r]);
                acc[r] = fmaf(v.z, wr2[4*k+2], acc[r]);
                acc[r] = fmaf(v.w, wr2[4*k+3], acc[r]);
            }
        }
        float* part = smem + YPL_ + 2048;
        if (kh == 1){
            #pragma unroll
            for (int r = 0; r < 8; ++r) part[(rg*8+r)*64 + c] = acc[r];
        }
        __syncthreads();
        if (kh == 0){
            float s = 0.f, ss = 0.f;
            #pragma unroll
            for (int r = 0; r < 8; ++r){
                float v = acc[r] + part[(rg*8+r)*64 + c];
                ys[(size_t)(ch*16 + rg*8 + r)*64 + c] = v;
                s += v; ss += v*v;
            }
            s += __shfl_xor(s,1); ss += __shfl_xor(ss,1);
            s += __shfl_xor(s,2); ss += __shfl_xor(ss,2);
            s += __shfl_xor(s,4); ss += __shfl_xor(ss,4);
            s += __shfl_xor(s,8); ss += __shfl_xor(ss,8);
            if ((c & 15) == 0){
                smem[PGS_ + 0*8 + rg*4 + (c>>4)] = s;
                smem[PGS_ + 16  + rg*4 + (c>>4)] = ss;
            }
        }
        __syncthreads();
        if (tid < 4){
            int b = ch >> 8, blk = ch & 255;
            float S  = smem[PGS_ + 0*8 + 0*4 + tid] + smem[PGS_ + 0*8 + 1*4 + tid];
            float SS = smem[PGS_ + 16  + 0*4 + tid] + smem[PGS_ + 16  + 1*4 + tid];
            float* dst = sp + (size_t)((b*4 + tid)*512 + blk*2);
            dst[0] = S; dst[1] = SS;
        }
    }
}

// ---- spe: per-pixel mamba; ALL per-lane weights staged to LDS ------------
#define XE_   0
#define XCL_  1216
#define BCL_  3904
#define DTV_  8640
#define SPG_  8768
#define WEIN_ 8800
#define WECW_ 9056
#define WECB_ 9120
#define WEAL_ 9136
#define WDTW_ 9392
#define WDTB_ 9408
#define WDV_  9424
__global__ void __launch_bounds__(256) k_spe(
        const float* __restrict__ x,
        const float* __restrict__ ein_w, const float* __restrict__ ecw, const float* __restrict__ ecb,
        const float* __restrict__ expw, const float* __restrict__ edtw, const float* __restrict__ edtb,
        const float* __restrict__ eA_log, const float* __restrict__ eDv, const float* __restrict__ eow,
        float* __restrict__ ye, float* __restrict__ sp)
{
    __shared__ float smem[9440];
    const int tid = threadIdx.x;
    const int pix = tid >> 4;
    const int d   = tid & 15;
    const int eb  = blockIdx.x;
    const int p0  = eb * 16;
    const int b   = p0 >> 12;
    const int hw0 = p0 & 4095;

    #pragma unroll
    for (int it = 0; it < 3; ++it){
        int idx = it*256 + tid;
        if (idx < 640){
            float v;
            if      (idx < 256) v = ein_w[idx];
            else if (idx < 320) v = ecw[idx-256];
            else if (idx < 336) v = ecb[idx-320];
            else if (idx < 592) v = eA_log[idx-336];
            else if (idx < 608) v = edtw[idx-592];
            else if (idx < 624) v = edtb[idx-608];
            else                v = eDv[idx-624];
            smem[WEIN_ + idx] = v;
        }
    }
    const float* xb = x + b*262144 + hw0;
    #pragma unroll
    for (int it = 0; it < 4; ++it){
        int idx = it*256 + tid;
        smem[XE_ + (idx&15)*76 + (idx>>4)] = xb[(idx>>4)*4096 + (idx&15)];
    }
    __syncthreads();

    float wi[8], wz[8];
    #pragma unroll
    for (int g = 0; g < 8; ++g){ wi[g] = smem[WEIN_ + d*8+g]; wz[g] = smem[WEIN_ + 128 + d*8+g]; }
    float xi[8], zz[8];
    {
        const float4* xe4 = (const float4*)(smem + XE_ + pix*76);
        #pragma unroll
        for (int t = 0; t < 8; ++t){
            float4 a = xe4[t*2], bq = xe4[t*2+1];
            float xv8[8] = {a.x,a.y,a.z,a.w,bq.x,bq.y,bq.z,bq.w};
            float ai = 0.f, az = 0.f;
            #pragma unroll
            for (int g = 0; g < 8; ++g){
                ai = fmaf(xv8[g], wi[g], ai);
                az = fmaf(xv8[g], wz[g], az);
            }
            xi[t] = ai; zz[t] = az;
        }
    }
    float c0 = smem[WECW_ + d*4+0], c1 = smem[WECW_ + d*4+1];
    float c2 = smem[WECW_ + d*4+2], c3 = smem[WECW_ + d*4+3];
    float cbd = smem[WECB_ + d];
    float xcr[8];
    #pragma unroll
    for (int t = 0; t < 8; ++t){
        float a = fmaf(c3, xi[t], cbd);
        if (t >= 1) a = fmaf(c2, xi[t-1], a);
        if (t >= 2) a = fmaf(c1, xi[t-2], a);
        if (t >= 3) a = fmaf(c0, xi[t-3], a);
        xcr[t] = siluf(a);
        smem[XCL_ + pix*168 + t*20 + d] = xcr[t];
    }
    __syncthreads();

    {
        const int row = tid & 127;
        const int jh  = tid >> 7;
        const int px2 = row >> 3;
        const int t2  = row & 7;
        const float4* xr = (const float4*)(smem + XCL_ + px2*168 + t2*20);
        float4 r0 = xr[0], r1 = xr[1], r2 = xr[2], r3 = xr[3];
        float xv[16] = {r0.x,r0.y,r0.z,r0.w, r1.x,r1.y,r1.z,r1.w,
                        r2.x,r2.y,r2.z,r2.w, r3.x,r3.y,r3.z,r3.w};
        const float* wbase = expw + (1 + jh*16)*16;
        float outv[16];
        #pragma unroll
        for (int s = 0; s < 16; ++s){
            const float* wr = wbase + s*16;
            float a = 0.f;
            #pragma unroll
            for (int k = 0; k < 16; ++k) a = fmaf(xv[k], wr[k], a);
            outv[s] = a;
        }
        float4* dst4 = (float4*)(smem + BCL_ + px2*296 + t2*36 + jh*16);
        dst4[0] = make_float4(outv[0], outv[1], outv[2], outv[3]);
        dst4[1] = make_float4(outv[4], outv[5], outv[6], outv[7]);
        dst4[2] = make_float4(outv[8], outv[9], outv[10],outv[11]);
        dst4[3] = make_float4(outv[12],outv[13],outv[14],outv[15]);
        if (jh == 0){
            float accd = 0.f;
            #pragma unroll
            for (int k = 0; k < 16; ++k) accd = fmaf(xv[k], expw[k], accd);
            smem[DTV_ + px2*8 + t2] = accd;
        }
    }
    __syncthreads();

    float A16[16];
    #pragma unroll
    for (int s = 0; s < 16; ++s) A16[s] = -__expf(smem[WEAL_ + d*16+s]) * 1.44269504f;
    float dwd = smem[WDTW_ + d], dbd = smem[WDTB_ + d], Dd = smem[WDV_ + d];
    float h[16];
    #pragma unroll
    for (int s = 0; s < 16; ++s) h[s] = 0.f;
    #pragma unroll
    for (int t = 0; t < 8; ++t){
        float dtd = softplusf(fmaf(smem[DTV_ + pix*8 + t], dwd, dbd));
        float db = dtd * xcr[t];
        const float4* bc4 = (const float4*)(smem + BCL_ + pix*296 + t*36);
        float4 b0 = bc4[0], b1 = bc4[1], b2 = bc4[2], b3 = bc4[3];
        float4 cc0 = bc4[4], cc1 = bc4[5], cc2 = bc4[6], cc3 = bc4[7];
        float bv[16] = {b0.x,b0.y,b0.z,b0.w, b1.x,b1.y,b1.z,b1.w,
                        b2.x,b2.y,b2.z,b2.w, b3.x,b3.y,b3.z,b3.w};
        float cv[16] = {cc0.x,cc0.y,cc0.z,cc0.w, cc1.x,cc1.y,cc1.z,cc1.w,
                        cc2.x,cc2.y,cc2.z,cc2.w, cc3.x,cc3.y,cc3.z,cc3.w};
        float yp = 0.f;
        #pragma unroll
        for (int s = 0; s < 16; ++s){
            float a = fexp2(dtd*A16[s]);
            h[s] = fmaf(a, h[s], db*bv[s]);
            yp = fmaf(h[s], cv[s], yp);
        }
        smem[pix*168 + t*20 + d] = (yp + xcr[t]*Dd) * siluf(zz[t]);
    }
    __syncthreads();

    {
        const int half = tid >> 7;
        const int idx7 = tid & 127;
        const int pixD = idx7 >> 3;
        const int ttD  = idx7 & 7;
        const int m0   = half*4;
        const float4* y4 = (const float4*)(smem + pixD*168 + ttD*20);
        float4 y0 = y4[0], y1 = y4[1], y2 = y4[2], y3 = y4[3];
        float ylr[16] = {y0.x,y0.y,y0.z,y0.w, y1.x,y1.y,y1.z,y1.w,
                         y2.x,y2.y,y2.z,y2.w, y3.x,y3.y,y3.z,y3.w};
        float acc[4];
        #pragma unroll
        for (int mm = 0; mm < 4; ++mm){
            const float* wr = eow + (m0+mm)*16;
            float a = 0.f;
            #pragma unroll
            for (int k = 0; k < 16; ++k) a = fmaf(ylr[k], wr[k], a);
            acc[mm] = a;
        }
        float4 o; o.x=acc[0]; o.y=acc[1]; o.z=acc[2]; o.w=acc[3];
        *(float4*)(ye + (size_t)(p0+pixD)*64 + ttD*8 + m0) = o;

        float s  = acc[0]+acc[1]+acc[2]+acc[3];
        float ss = acc[0]*acc[0]+acc[1]*acc[1]+acc[2]*acc[2]+acc[3]*acc[3];
        s += __shfl_xor(s,1);  ss += __shfl_xor(ss,1);
        s += __shfl_xor(s,8);  ss += __shfl_xor(ss,8);
        s += __shfl_xor(s,16); ss += __shfl_xor(ss,16);
        s += __shfl_xor(s,32); ss += __shfl_xor(ss,32);
        int lane = tid & 63, wv = tid >> 6;
        if ((lane & 57) == 0){
            smem[SPG_ + wv*4 + ((lane>>1)&3)] = s;
            smem[SPG_ + 16 + wv*4 + ((lane>>1)&3)] = ss;
        }
    }
    __syncthreads();
    if (tid < 4){
        int blk = eb & 255;
        float S  = smem[SPG_+0*4+tid]+smem[SPG_+1*4+tid]+smem[SPG_+2*4+tid]+smem[SPG_+3*4+tid];
        float SS = smem[SPG_+16+0*4+tid]+smem[SPG_+16+1*4+tid]+smem[SPG_+16+2*4+tid]+smem[SPG_+16+3*4+tid];
        float* dst = sp + (size_t)(((4 + b)*4 + tid)*512 + blk*2);
        dst[0] = S; dst[1] = SS;
    }
}

// ---- final: reduce GN partials (256 slices each), normalize, combine -----
__global__ void __launch_bounds__(256) k_final(const float* __restrict__ x,
        const float* __restrict__ ys, const float* __restrict__ ye,
        const float* __restrict__ sp,
        const float* __restrict__ gsw, const float* __restrict__ gsb,
        const float* __restrict__ gew, const float* __restrict__ geb,
        const float* __restrict__ attw, float* __restrict__ out){
    __shared__ float st[16];
    __shared__ float tys[32][65];
    __shared__ float tye[32][65];
    int tid = threadIdx.x;
    int b   = blockIdx.x >> 7;
    int hw0 = (blockIdx.x & 127) << 5;
    {
        int combo = tid >> 5;        // t*4+g
        int j = tid & 31;
        int t = combo >> 2, g = combo & 3;
        const float4* bp = (const float4*)(sp + (size_t)(t*16 + b*4 + g)*512 + j*16);
        float s = 0.f, ss = 0.f;
        #pragma unroll
        for (int k = 0; k < 4; ++k){ float4 v = bp[k]; s += v.x+v.z; ss += v.y+v.w; }
        s += __shfl_xor(s,1);  ss += __shfl_xor(ss,1);
        s += __shfl_xor(s,2);  ss += __shfl_xor(ss,2);
        s += __shfl_xor(s,4);  ss += __shfl_xor(ss,4);
        s += __shfl_xor(s,8);  ss += __shfl_xor(ss,8);
        s += __shfl_xor(s,16); ss += __shfl_xor(ss,16);
        if (j == 0){
            float m = s * (1.f/65536.f);
            float v = ss * (1.f/65536.f) - m*m;
            st[combo*2]   = m;
            st[combo*2+1] = rsqrtf(v + 1e-5f);
        }
    }
    const float* ysb = ys + ((size_t)(b*4096 + hw0))*64;
    const float* yeb = ye + ((size_t)(b*4096 + hw0))*64;
    #pragma unroll
    for (int it = 0; it < 8; ++it){
        int idx = it*256 + tid;
        tys[idx>>6][idx&63] = ysb[idx];
        tye[idx>>6][idx&63] = yeb[idx];
    }
    __syncthreads();
    float a0 = attw[0], a1 = attw[1];
    float mx = fmaxf(a0, a1);
    float e0 = __expf(a0-mx), e1 = __expf(a1-mx);
    float inv = 1.f/(e0+e1);
    float w0 = e0*inv, w1 = e1*inv;
    #pragma unroll
    for (int it = 0; it < 8; ++it){
        int idx = it*256 + tid;
        int c = idx >> 5, hwi = idx & 31;
        int g = c >> 4;
        size_t gx = ((size_t)(b*64 + c))*4096 + hw0 + hwi;
        float xv = x[gx];
        float ns = (tys[hwi][c] - st[g*2])     * st[g*2+1]     * gsw[c] + gsb[c];
        float ne = (tye[hwi][c] - st[8+g*2])   * st[8+g*2+1]   * gew[c] + geb[c];
        out[gx] = w0*(siluf(ns)+xv) + w1*(xv+siluf(ne)) + xv;
    }
}

// ---- workspace layout (floats) ------------------------------------------
#define OFF_YS 0u           // 1,048,576
#define OFF_PB 1048576u     // 2,097,152 (1024 units x 2048)
#define OFF_QB 3145728u     // 2,097,152
#define OFF_HS 5242880u     // 2,097,152
#define OFF_YE 7340032u     // 1,048,576
#define OFF_PS 8388608u     // 32,768
#define OFF_QS 8421376u     // 32,768
#define OFF_SP 8454144u     // 16,384

extern "C" void kernel_launch(void* const* d_in, const int* in_sizes, int n_in,
                              void* d_out, int out_size, void* d_ws, size_t ws_size,
                              hipStream_t stream) {
    const float* x           = (const float*)d_in[0];
    const float* spa_in_w    = (const float*)d_in[1];
    const float* spa_conv_w  = (const float*)d_in[2];
    const float* spa_conv_b  = (const float*)d_in[3];
    const float* spa_xproj_w = (const float*)d_in[4];
    const float* spa_dt_w    = (const float*)d_in[5];
    const float* spa_dt_b    = (const float*)d_in[6];
    const float* spa_A_log   = (const float*)d_in[7];
    const float* spa_D       = (const float*)d_in[8];
    const float* spa_out_w   = (const float*)d_in[9];
    const float* spe_in_w    = (const float*)d_in[10];
    const float* spe_conv_w  = (const float*)d_in[11];
    const float* spe_conv_b  = (const float*)d_in[12];
    const float* spe_xproj_w = (const float*)d_in[13];
    const float* spe_dt_w    = (const float*)d_in[14];
    const float* spe_dt_b    = (const float*)d_in[15];
    const float* spe_A_log   = (const float*)d_in[16];
    const float* spe_D       = (const float*)d_in[17];
    const float* spe_out_w   = (const float*)d_in[18];
    const float* spa_gn_w    = (const float*)d_in[19];
    const float* spa_gn_b    = (const float*)d_in[20];
    const float* spe_gn_w    = (const float*)d_in[21];
    const float* spe_gn_b    = (const float*)d_in[22];
    const float* att_w       = (const float*)d_in[23];

    float* ws  = (float*)d_ws;
    float* Pb  = ws + OFF_PB;
    float* Qb  = ws + OFF_QB;
    float* Hs  = ws + OFF_HS;
    float* Ps  = ws + OFF_PS;
    float* Qs  = ws + OFF_QS;
    float* sp  = ws + OFF_SP;
    float* ysb = ws + OFF_YS;
    float* yeb = ws + OFF_YE;
    float* out = (float*)d_out;

    k_spe<<<1024, 256, 0, stream>>>(x, spe_in_w, spe_conv_w, spe_conv_b, spe_xproj_w,
                                    spe_dt_w, spe_dt_b, spe_A_log, spe_D, spe_out_w,
                                    yeb, sp);
    {
        void* args[17] = {
            (void*)&x, (void*)&spa_in_w, (void*)&spa_conv_w, (void*)&spa_conv_b,
            (void*)&spa_xproj_w, (void*)&spa_dt_w, (void*)&spa_dt_b, (void*)&spa_A_log,
            (void*)&spa_D, (void*)&spa_out_w,
            (void*)&Pb, (void*)&Qb, (void*)&Ps, (void*)&Qs, (void*)&Hs,
            (void*)&ysb, (void*)&sp };
        hipLaunchCooperativeKernel(k_spa_coop, dim3(1024), dim3(256), args, 0u, stream);
    }
    k_final<<<512, 256, 0, stream>>>(x, ysb, yeb, sp, spa_gn_w, spa_gn_b,
                                     spe_gn_w, spe_gn_b, att_w, out);
}

// Round 12
// 118.394 us; speedup vs baseline: 5.8574x; 5.8574x over previous
//
#include <hip/hip_runtime.h>

__device__ __forceinline__ float siluf(float x){ return x / (1.f + __expf(-x)); }
__device__ __forceinline__ float softplusf(float x){
    return fmaxf(x, 0.f) + __logf(1.f + __expf(-fabsf(x)));
}
#if __has_builtin(__builtin_amdgcn_exp2f)
__device__ __forceinline__ float fexp2(float x){ return __builtin_amdgcn_exp2f(x); }
#else
__device__ __forceinline__ float fexp2(float x){ return exp2f(x); }
#endif

// ---- spa in_proj + causal conv + SiLU, self-staging transpose ------------
__global__ void __launch_bounds__(256) k_inproj_conv(const float* __restrict__ x,
        const float* __restrict__ in_w, const float* __restrict__ cw, const float* __restrict__ cb,
        float* __restrict__ xc, float* __restrict__ zb){
    __shared__ float sxe[11][68];
    int tid = threadIdx.x;
    int l0 = blockIdx.x * 8;
    #pragma unroll
    for (int it = 0; it < 3; ++it){
        int idx = it*256 + tid;
        if (idx < 704){
            int r = idx >> 6, c = idx & 63;
            int p = l0 - 3 + r;
            float v = 0.f;
            if (p >= 0) v = x[(size_t)(p >> 12)*262144 + c*4096 + (p & 4095)];
            sxe[r][c] = v;
        }
    }
    float wr[64];
    const float4* w4 = (const float4*)(in_w + tid*64);
    #pragma unroll
    for (int k = 0; k < 16; ++k){
        float4 v = w4[k];
        wr[4*k]=v.x; wr[4*k+1]=v.y; wr[4*k+2]=v.z; wr[4*k+3]=v.w;
    }
    __syncthreads();
    if (tid < 128){
        float acc[11];
        #pragma unroll
        for (int r = 0; r < 11; ++r) acc[r] = 0.f;
        #pragma unroll
        for (int k = 0; k < 16; ++k){
            #pragma unroll
            for (int r = 0; r < 11; ++r){
                float4 v = *(const float4*)&sxe[r][4*k];
                acc[r] = fmaf(v.x, wr[4*k],   acc[r]);
                acc[r] = fmaf(v.y, wr[4*k+1], acc[r]);
                acc[r] = fmaf(v.z, wr[4*k+2], acc[r]);
                acc[r] = fmaf(v.w, wr[4*k+3], acc[r]);
            }
        }
        float cw0 = cw[tid*4+0], cw1 = cw[tid*4+1], cw2 = cw[tid*4+2], cw3 = cw[tid*4+3];
        float cbd = cb[tid];
        #pragma unroll
        for (int r = 0; r < 8; ++r){
            float a = fmaf(cw0, acc[r],   cbd);
            a = fmaf(cw1, acc[r+1], a);
            a = fmaf(cw2, acc[r+2], a);
            a = fmaf(cw3, acc[r+3], a);
            xc[(size_t)(l0+r)*128 + tid] = siluf(a);
        }
    } else {
        float acc[8];
        #pragma unroll
        for (int r = 0; r < 8; ++r) acc[r] = 0.f;
        #pragma unroll
        for (int k = 0; k < 16; ++k){
            #pragma unroll
            for (int r = 0; r < 8; ++r){
                float4 v = *(const float4*)&sxe[r+3][4*k];
                acc[r] = fmaf(v.x, wr[4*k],   acc[r]);
                acc[r] = fmaf(v.y, wr[4*k+1], acc[r]);
                acc[r] = fmaf(v.z, wr[4*k+2], acc[r]);
                acc[r] = fmaf(v.w, wr[4*k+3], acc[r]);
            }
        }
        int dz = tid - 128;
        #pragma unroll
        for (int r = 0; r < 8; ++r) zb[(size_t)(l0+r)*128 + dz] = acc[r];
    }
}

// ---- spa scan p1: 16-token chunks, OWN kernel, small LDS -> 100% occ -----
__global__ void __launch_bounds__(256) k_scan_p1(const float* __restrict__ xc,
        const float* __restrict__ xpw, const float* __restrict__ dtw, const float* __restrict__ dtb,
        const float* __restrict__ A_log, float* __restrict__ Pb, float* __restrict__ Qb){
    __shared__ float sxc[2048];
    __shared__ float sbm[256];
    __shared__ __align__(16) float dtr[64];
    const int tid = threadIdx.x;
    const int ch = blockIdx.x;    // 16-token unit index, 0..1023
    {
        const float4* src = (const float4*)(xc + (size_t)ch*2048);
        float4* dst = (float4*)sxc;
        dst[tid] = src[tid];
        dst[256 + tid] = src[256 + tid];
    }
    __syncthreads();
    {
        int j = tid & 63, tg = tid >> 6;     // 4 token-groups x 4 tokens
        if (j < 20){
            const float4* w4  = (const float4*)(xpw + j*128);
            const float4* xc4 = (const float4*)sxc + tg*128;
            float acc[4];
            #pragma unroll
            for (int r = 0; r < 4; ++r) acc[r] = 0.f;
            #pragma unroll 8
            for (int k = 0; k < 32; ++k){
                float4 w = w4[k];
                #pragma unroll
                for (int r = 0; r < 4; ++r){
                    float4 v = xc4[r*32 + k];
                    acc[r] = fmaf(v.x, w.x, acc[r]);
                    acc[r] = fmaf(v.y, w.y, acc[r]);
                    acc[r] = fmaf(v.z, w.z, acc[r]);
                    acc[r] = fmaf(v.w, w.w, acc[r]);
                }
            }
            if (j < 4){
                #pragma unroll
                for (int r = 0; r < 4; ++r) dtr[(tg*4+r)*4 + j] = acc[r];
            } else {
                #pragma unroll
                for (int r = 0; r < 4; ++r) sbm[(tg*4+r)*16 + (j-4)] = acc[r];
            }
        }
    }
    __syncthreads();
    const int d  = tid & 127;
    const int sh = tid >> 7;
    float A8[8];
    {
        const float4* al4 = (const float4*)(A_log + d*16 + sh*8);
        float4 v0 = al4[0], v1 = al4[1];
        A8[0]=-__expf(v0.x)*1.44269504f; A8[1]=-__expf(v0.y)*1.44269504f;
        A8[2]=-__expf(v0.z)*1.44269504f; A8[3]=-__expf(v0.w)*1.44269504f;
        A8[4]=-__expf(v1.x)*1.44269504f; A8[5]=-__expf(v1.y)*1.44269504f;
        A8[6]=-__expf(v1.z)*1.44269504f; A8[7]=-__expf(v1.w)*1.44269504f;
    }
    float4 dw = *(const float4*)(dtw + d*4);
    float dbd = dtb[d];
    float P[8], Q[8];
    #pragma unroll
    for (int s = 0; s < 8; ++s){ P[s] = 1.f; Q[s] = 0.f; }
    #pragma unroll 4
    for (int i = 0; i < 16; ++i){
        float4 dt4 = *(const float4*)(dtr + i*4);
        float dv = dbd;
        dv = fmaf(dt4.x, dw.x, dv);
        dv = fmaf(dt4.y, dw.y, dv);
        dv = fmaf(dt4.z, dw.z, dv);
        dv = fmaf(dt4.w, dw.w, dv);
        float dt = softplusf(dv);
        float db = dt * sxc[i*128 + d];
        const float4* bmr = (const float4*)(sbm + i*16 + sh*8);
        float4 b0 = bmr[0], b1 = bmr[1];
        float bv[8] = {b0.x,b0.y,b0.z,b0.w,b1.x,b1.y,b1.z,b1.w};
        #pragma unroll
        for (int s = 0; s < 8; ++s){
            float a = fexp2(dt*A8[s]);
            P[s] *= a;
            Q[s] = fmaf(a, Q[s], db*bv[s]);
        }
    }
    float* Pp = Pb + (size_t)ch*2048 + d*16 + sh*8;
    float* Qp = Qb + (size_t)ch*2048 + d*16 + sh*8;
    ((float4*)Pp)[0] = make_float4(P[0],P[1],P[2],P[3]);
    ((float4*)Pp)[1] = make_float4(P[4],P[5],P[6],P[7]);
    ((float4*)Qp)[0] = make_float4(Q[0],Q[1],Q[2],Q[3]);
    ((float4*)Qp)[1] = make_float4(Q[4],Q[5],Q[6],Q[7]);
}

// ---- spe: per-pixel mamba; ALL per-lane weights staged to LDS ------------
#define XE_   0
#define XCL_  1216
#define BCL_  3904
#define DTV_  8640
#define SPG_  8768
#define WEIN_ 8800       // ein_w 256
#define WECW_ 9056       // ecw 64
#define WECB_ 9120       // ecb 16
#define WEAL_ 9136       // eA_log 256
#define WDTW_ 9392       // edtw 16
#define WDTB_ 9408       // edtb 16
#define WDV_  9424       // eDv 16  -> total 9440 floats (37.8 KB)
__global__ void __launch_bounds__(256) k_spe(
        const float* __restrict__ x,
        const float* __restrict__ ein_w, const float* __restrict__ ecw, const float* __restrict__ ecb,
        const float* __restrict__ expw, const float* __restrict__ edtw, const float* __restrict__ edtb,
        const float* __restrict__ eA_log, const float* __restrict__ eDv, const float* __restrict__ eow,
        float* __restrict__ ye, float* __restrict__ sp)
{
    __shared__ float smem[9440];
    const int tid = threadIdx.x;
    const int pix = tid >> 4;
    const int d   = tid & 15;
    const int eb  = blockIdx.x;
    const int p0  = eb * 16;
    const int b   = p0 >> 12;
    const int hw0 = p0 & 4095;

    // stage weights (640 floats, coalesced) + xe tile
    #pragma unroll
    for (int it = 0; it < 3; ++it){
        int idx = it*256 + tid;
        if (idx < 640){
            float v;
            if      (idx < 256) v = ein_w[idx];
            else if (idx < 320) v = ecw[idx-256];
            else if (idx < 336) v = ecb[idx-320];
            else if (idx < 592) v = eA_log[idx-336];
            else if (idx < 608) v = edtw[idx-592];
            else if (idx < 624) v = edtb[idx-608];
            else                v = eDv[idx-624];
            smem[WEIN_ + idx] = v;
        }
    }
    const float* xb = x + b*262144 + hw0;
    #pragma unroll
    for (int it = 0; it < 4; ++it){
        int idx = it*256 + tid;
        smem[XE_ + (idx&15)*76 + (idx>>4)] = xb[(idx>>4)*4096 + (idx&15)];
    }
    __syncthreads();

    float wi[8], wz[8];
    #pragma unroll
    for (int g = 0; g < 8; ++g){ wi[g] = smem[WEIN_ + d*8+g]; wz[g] = smem[WEIN_ + 128 + d*8+g]; }
    float xi[8], zz[8];
    {
        const float4* xe4 = (const float4*)(smem + XE_ + pix*76);
        #pragma unroll
        for (int t = 0; t < 8; ++t){
            float4 a = xe4[t*2], bq = xe4[t*2+1];
            float xv8[8] = {a.x,a.y,a.z,a.w,bq.x,bq.y,bq.z,bq.w};
            float ai = 0.f, az = 0.f;
            #pragma unroll
            for (int g = 0; g < 8; ++g){
                ai = fmaf(xv8[g], wi[g], ai);
                az = fmaf(xv8[g], wz[g], az);
            }
            xi[t] = ai; zz[t] = az;
        }
    }
    float c0 = smem[WECW_ + d*4+0], c1 = smem[WECW_ + d*4+1];
    float c2 = smem[WECW_ + d*4+2], c3 = smem[WECW_ + d*4+3];
    float cbd = smem[WECB_ + d];
    float xcr[8];
    #pragma unroll
    for (int t = 0; t < 8; ++t){
        float a = fmaf(c3, xi[t], cbd);
        if (t >= 1) a = fmaf(c2, xi[t-1], a);
        if (t >= 2) a = fmaf(c1, xi[t-2], a);
        if (t >= 3) a = fmaf(c0, xi[t-3], a);
        xcr[t] = siluf(a);
        smem[XCL_ + pix*168 + t*20 + d] = xcr[t];
    }
    __syncthreads();

    // phase B: x_proj. row = tid&127 = (px2,t2); jh = tid>>7 (wave-uniform)
    {
        const int row = tid & 127;
        const int jh  = tid >> 7;
        const int px2 = row >> 3;
        const int t2  = row & 7;
        const float4* xr = (const float4*)(smem + XCL_ + px2*168 + t2*20);
        float4 r0 = xr[0], r1 = xr[1], r2 = xr[2], r3 = xr[3];
        float xv[16] = {r0.x,r0.y,r0.z,r0.w, r1.x,r1.y,r1.z,r1.w,
                        r2.x,r2.y,r2.z,r2.w, r3.x,r3.y,r3.z,r3.w};
        const float* wbase = expw + (1 + jh*16)*16;
        float outv[16];
        #pragma unroll
        for (int s = 0; s < 16; ++s){
            const float* wr = wbase + s*16;
            float a = 0.f;
            #pragma unroll
            for (int k = 0; k < 16; ++k) a = fmaf(xv[k], wr[k], a);
            outv[s] = a;
        }
        float4* dst4 = (float4*)(smem + BCL_ + px2*296 + t2*36 + jh*16);
        dst4[0] = make_float4(outv[0], outv[1], outv[2], outv[3]);
        dst4[1] = make_float4(outv[4], outv[5], outv[6], outv[7]);
        dst4[2] = make_float4(outv[8], outv[9], outv[10],outv[11]);
        dst4[3] = make_float4(outv[12],outv[13],outv[14],outv[15]);
        if (jh == 0){
            float accd = 0.f;
            #pragma unroll
            for (int k = 0; k < 16; ++k) accd = fmaf(xv[k], expw[k], accd);
            smem[DTV_ + px2*8 + t2] = accd;
        }
    }
    __syncthreads();

    // phase C: scan (thread = pix,d)
    float A16[16];
    #pragma unroll
    for (int s = 0; s < 16; ++s) A16[s] = -__expf(smem[WEAL_ + d*16+s]) * 1.44269504f;
    float dwd = smem[WDTW_ + d], dbd = smem[WDTB_ + d], Dd = smem[WDV_ + d];
    float h[16];
    #pragma unroll
    for (int s = 0; s < 16; ++s) h[s] = 0.f;
    #pragma unroll
    for (int t = 0; t < 8; ++t){
        float dtd = softplusf(fmaf(smem[DTV_ + pix*8 + t], dwd, dbd));
        float db = dtd * xcr[t];
        const float4* bc4 = (const float4*)(smem + BCL_ + pix*296 + t*36);
        float4 b0 = bc4[0], b1 = bc4[1], b2 = bc4[2], b3 = bc4[3];
        float4 cc0 = bc4[4], cc1 = bc4[5], cc2 = bc4[6], cc3 = bc4[7];
        float bv[16] = {b0.x,b0.y,b0.z,b0.w, b1.x,b1.y,b1.z,b1.w,
                        b2.x,b2.y,b2.z,b2.w, b3.x,b3.y,b3.z,b3.w};
        float cv[16] = {cc0.x,cc0.y,cc0.z,cc0.w, cc1.x,cc1.y,cc1.z,cc1.w,
                        cc2.x,cc2.y,cc2.z,cc2.w, cc3.x,cc3.y,cc3.z,cc3.w};
        float yp = 0.f;
        #pragma unroll
        for (int s = 0; s < 16; ++s){
            float a = fexp2(dtd*A16[s]);
            h[s] = fmaf(a, h[s], db*bv[s]);
            yp = fmaf(h[s], cv[s], yp);
        }
        smem[pix*168 + t*20 + d] = (yp + xcr[t]*Dd) * siluf(zz[t]);
    }
    __syncthreads();

    // phase D: out_proj. half = tid>>7 (wave-uniform m-quad)
    {
        const int half = tid >> 7;
        const int idx7 = tid & 127;
        const int pixD = idx7 >> 3;
        const int ttD  = idx7 & 7;
        const int m0   = half*4;
        const float4* y4 = (const float4*)(smem + pixD*168 + ttD*20);
        float4 y0 = y4[0], y1 = y4[1], y2 = y4[2], y3 = y4[3];
        float ylr[16] = {y0.x,y0.y,y0.z,y0.w, y1.x,y1.y,y1.z,y1.w,
                         y2.x,y2.y,y2.z,y2.w, y3.x,y3.y,y3.z,y3.w};
        float acc[4];
        #pragma unroll
        for (int mm = 0; mm < 4; ++mm){
            const float* wr = eow + (m0+mm)*16;
            float a = 0.f;
            #pragma unroll
            for (int k = 0; k < 16; ++k) a = fmaf(ylr[k], wr[k], a);
            acc[mm] = a;
        }
        float4 o; o.x=acc[0]; o.y=acc[1]; o.z=acc[2]; o.w=acc[3];
        *(float4*)(ye + (size_t)(p0+pixD)*64 + ttD*8 + m0) = o;

        float s  = acc[0]+acc[1]+acc[2]+acc[3];
        float ss = acc[0]*acc[0]+acc[1]*acc[1]+acc[2]*acc[2]+acc[3]*acc[3];
        s += __shfl_xor(s,1);  ss += __shfl_xor(ss,1);
        s += __shfl_xor(s,8);  ss += __shfl_xor(ss,8);
        s += __shfl_xor(s,16); ss += __shfl_xor(ss,16);
        s += __shfl_xor(s,32); ss += __shfl_xor(ss,32);
        int lane = tid & 63, wv = tid >> 6;
        if ((lane & 57) == 0){   // g = (lane>>1)&3
            smem[SPG_ + wv*4 + ((lane>>1)&3)] = s;
            smem[SPG_ + 16 + wv*4 + ((lane>>1)&3)] = ss;
        }
    }
    __syncthreads();
    if (tid < 4){
        int blk = eb & 255;
        float S  = smem[SPG_+0*4+tid]+smem[SPG_+1*4+tid]+smem[SPG_+2*4+tid]+smem[SPG_+3*4+tid];
        float SS = smem[SPG_+16+0*4+tid]+smem[SPG_+16+1*4+tid]+smem[SPG_+16+2*4+tid]+smem[SPG_+16+3*4+tid];
        float* dst = sp + (size_t)(((4 + b)*4 + tid)*512 + blk*2);
        dst[0] = S; dst[1] = SS;
    }
}

// ---- scan pass 2a: compose 64 half-chunk units per super (16 supers) -----
__global__ void __launch_bounds__(256) k_scan_p2a(const float* __restrict__ Pb,
        const float* __restrict__ Qb, float* __restrict__ Ps, float* __restrict__ Qs){
    int g = blockIdx.x*256 + threadIdx.x;   // 0..32767
    int sup = g >> 11;
    int lane = g & 2047;
    float P = 1.f, Q = 0.f;
    for (int i = 0; i < 64; i += 8){
        float p[8], q[8];
        #pragma unroll
        for (int u = 0; u < 8; ++u){
            p[u] = Pb[(size_t)(sup*64+i+u)*2048 + lane];
            q[u] = Qb[(size_t)(sup*64+i+u)*2048 + lane];
        }
        #pragma unroll
        for (int u = 0; u < 8; ++u){
            P = p[u]*P;
            Q = fmaf(p[u], Q, q[u]);
        }
    }
    Ps[g] = P; Qs[g] = Q;
}

// ---- scan pass 2c: unit-level prefix (1024 units); Hsup inline -----------
__global__ void __launch_bounds__(256) k_scan_p2c(const float* __restrict__ Pb,
        const float* __restrict__ Qb, const float* __restrict__ Ps,
        const float* __restrict__ Qs, float* __restrict__ Hs){
    int g = blockIdx.x*256 + threadIdx.x;
    int sup = g >> 11;                 // block-uniform
    int lane = g & 2047;
    float h = 0.f;
    for (int u = 0; u < sup; ++u){
        float p = Ps[u*2048 + lane];
        float q = Qs[u*2048 + lane];
        h = fmaf(p, h, q);
    }
    for (int i = 0; i < 64; i += 8){
        float p[8], q[8];
        #pragma unroll
        for (int u = 0; u < 8; ++u){
            p[u] = Pb[(size_t)(sup*64+i+u)*2048 + lane];
            q[u] = Qb[(size_t)(sup*64+i+u)*2048 + lane];
        }
        #pragma unroll
        for (int u = 0; u < 8; ++u){
            Hs[(size_t)(sup*64+i+u)*2048 + lane] = h;
            h = fmaf(p[u], h, q[u]);
        }
    }
}

// ---- spa scan pass 3: 16-token chunks (1024 blocks), h0 from Hs, fused
//      x_proj (dt+B+C), gate, D-skip, out_proj + GN partials ---------------
__global__ void __launch_bounds__(256) k_scan_p3(const float* __restrict__ xc,
        const float* __restrict__ zb, const float* __restrict__ xpw, const float* __restrict__ dtw,
        const float* __restrict__ dtb, const float* __restrict__ A_log, const float* __restrict__ Dv,
        const float* __restrict__ Hs, const float* __restrict__ ow,
        float* __restrict__ ys, float* __restrict__ sp){
    __shared__ float sxc[16*128];
    __shared__ float ypl[2][16*128];
    __shared__ float sbm[16*16];
    __shared__ float scm[16*16];
    __shared__ __align__(16) float dtr[16][4];
    __shared__ float pgs[2][2][4];
    const int tid = threadIdx.x;
    const int ch = blockIdx.x;            // 0..1023
    {
        const float4* src = (const float4*)(xc + (size_t)ch*2048);
        float4* dst = (float4*)sxc;
        dst[tid] = src[tid];
        dst[256 + tid] = src[256 + tid];
    }
    __syncthreads();
    {
        int j = tid & 63, tg = tid >> 6;
        if (j < 36){
            const float4* w4  = (const float4*)(xpw + j*128);
            const float4* xc4 = (const float4*)sxc + tg*128;   // 4 tokens x 32 f4
            float acc[4];
            #pragma unroll
            for (int r = 0; r < 4; ++r) acc[r] = 0.f;
            #pragma unroll 8
            for (int k = 0; k < 32; ++k){
                float4 w = w4[k];
                #pragma unroll
                for (int r = 0; r < 4; ++r){
                    float4 v = xc4[r*32 + k];
                    acc[r] = fmaf(v.x, w.x, acc[r]);
                    acc[r] = fmaf(v.y, w.y, acc[r]);
                    acc[r] = fmaf(v.z, w.z, acc[r]);
                    acc[r] = fmaf(v.w, w.w, acc[r]);
                }
            }
            if (j < 4){
                #pragma unroll
                for (int r = 0; r < 4; ++r) dtr[tg*4+r][j] = acc[r];
            } else if (j < 20){
                #pragma unroll
                for (int r = 0; r < 4; ++r) sbm[(tg*4+r)*16 + (j-4)] = acc[r];
            } else {
                #pragma unroll
                for (int r = 0; r < 4; ++r) scm[(tg*4+r)*16 + (j-20)] = acc[r];
            }
        }
    }
    __syncthreads();
    const int d  = tid & 127;
    const int sh = tid >> 7;
    float A8[8], h[8];
    {
        const float4* al4 = (const float4*)(A_log + d*16 + sh*8);
        float4 v0 = al4[0], v1 = al4[1];
        A8[0]=-__expf(v0.x)*1.44269504f; A8[1]=-__expf(v0.y)*1.44269504f;
        A8[2]=-__expf(v0.z)*1.44269504f; A8[3]=-__expf(v0.w)*1.44269504f;
        A8[4]=-__expf(v1.x)*1.44269504f; A8[5]=-__expf(v1.y)*1.44269504f;
        A8[6]=-__expf(v1.z)*1.44269504f; A8[7]=-__expf(v1.w)*1.44269504f;
        const float4* h4 = (const float4*)(Hs + (size_t)ch*2048 + d*16 + sh*8);
        float4 h0 = h4[0], h1 = h4[1];
        h[0]=h0.x; h[1]=h0.y; h[2]=h0.z; h[3]=h0.w;
        h[4]=h1.x; h[5]=h1.y; h[6]=h1.z; h[7]=h1.w;
    }
    float4 dw = *(const float4*)(dtw + d*4);
    float dbd = dtb[d];
    #pragma unroll 4
    for (int i = 0; i < 16; ++i){
        float4 dt4 = *(const float4*)dtr[i];
        float dv = dbd;
        dv = fmaf(dt4.x, dw.x, dv);
        dv = fmaf(dt4.y, dw.y, dv);
        dv = fmaf(dt4.z, dw.z, dv);
        dv = fmaf(dt4.w, dw.w, dv);
        float dt = softplusf(dv);
        float db = dt * sxc[i*128 + d];
        const float4* bmr = (const float4*)(sbm + i*16 + sh*8);
        const float4* cmr = (const float4*)(scm + i*16 + sh*8);
        float4 b0 = bmr[0], b1 = bmr[1];
        float4 c0 = cmr[0], c1 = cmr[1];
        float bv[8] = {b0.x,b0.y,b0.z,b0.w,b1.x,b1.y,b1.z,b1.w};
        float cv[8] = {c0.x,c0.y,c0.z,c0.w,c1.x,c1.y,c1.z,c1.w};
        float yp = 0.f;
        #pragma unroll
        for (int s = 0; s < 8; ++s){
            float a = fexp2(dt*A8[s]);
            h[s] = fmaf(a, h[s], db*bv[s]);
            yp = fmaf(h[s], cv[s], yp);
        }
        ypl[sh][i*128 + d] = yp;
    }
    __syncthreads();
    #pragma unroll
    for (int it = 0; it < 8; ++it){
        int idx = it*256 + tid;
        float yp = ypl[0][idx] + ypl[1][idx];
        float xcd = sxc[idx];
        float zv = zb[(size_t)ch*2048 + idx];
        ypl[0][idx] = (yp + xcd*Dv[idx & 127]) * siluf(zv);
    }
    __syncthreads();
    // out_proj: [16 x 128] @ [128 -> 64], k-split 2, partials via ypl[1]
    {
        int c  = tid & 63;
        int kh = (tid >> 6) & 1;
        int rg = tid >> 7;                // 2 row groups x 8 rows
        float wr[64];
        const float4* w4o = (const float4*)(ow + c*128 + kh*64);
        #pragma unroll
        for (int k = 0; k < 16; ++k){
            float4 v = w4o[k];
            wr[4*k]=v.x; wr[4*k+1]=v.y; wr[4*k+2]=v.z; wr[4*k+3]=v.w;
        }
        float acc[8];
        #pragma unroll
        for (int r = 0; r < 8; ++r) acc[r] = 0.f;
        const float4* y4 = (const float4*)(ypl[0] + rg*8*128 + kh*64);
        #pragma unroll
        for (int k = 0; k < 16; ++k){
            #pragma unroll
            for (int r = 0; r < 8; ++r){
                float4 v = y4[r*32 + k];
                acc[r] = fmaf(v.x, wr[4*k],   acc[r]);
                acc[r] = fmaf(v.y, wr[4*k+1], acc[r]);
                acc[r] = fmaf(v.z, wr[4*k+2], acc[r]);
                acc[r] = fmaf(v.w, wr[4*k+3], acc[r]);
            }
        }
        float* part = ypl[1];
        if (kh == 1){
            #pragma unroll
            for (int r = 0; r < 8; ++r) part[(rg*8+r)*64 + c] = acc[r];
        }
        __syncthreads();
        if (kh == 0){
            float s = 0.f, ss = 0.f;
            #pragma unroll
            for (int r = 0; r < 8; ++r){
                float v = acc[r] + part[(rg*8+r)*64 + c];
                ys[(size_t)(ch*16 + rg*8 + r)*64 + c] = v;
                s += v; ss += v*v;
            }
            s += __shfl_xor(s,1); ss += __shfl_xor(ss,1);
            s += __shfl_xor(s,2); ss += __shfl_xor(ss,2);
            s += __shfl_xor(s,4); ss += __shfl_xor(ss,4);
            s += __shfl_xor(s,8); ss += __shfl_xor(ss,8);
            if ((c & 15) == 0){ pgs[0][rg][c>>4] = s; pgs[1][rg][c>>4] = ss; }
        }
        __syncthreads();
        if (tid < 4){
            int b = ch >> 8, blk = ch & 255;
            float S  = pgs[0][0][tid] + pgs[0][1][tid];
            float SS = pgs[1][0][tid] + pgs[1][1][tid];
            float* dst = sp + (size_t)((b*4 + tid)*512 + blk*2);
            dst[0] = S; dst[1] = SS;
        }
    }
}

// ---- final: reduce GN partials (256 slices each), normalize, combine -----
__global__ void __launch_bounds__(256) k_final(const float* __restrict__ x,
        const float* __restrict__ ys, const float* __restrict__ ye,
        const float* __restrict__ sp,
        const float* __restrict__ gsw, const float* __restrict__ gsb,
        const float* __restrict__ gew, const float* __restrict__ geb,
        const float* __restrict__ attw, float* __restrict__ out){
    __shared__ float st[16];         // 8 combos (t*4+g) x {mean, rstd}
    __shared__ float tys[32][65];
    __shared__ float tye[32][65];
    int tid = threadIdx.x;
    int b   = blockIdx.x >> 7;
    int hw0 = (blockIdx.x & 127) << 5;
    {
        int combo = tid >> 5;        // t*4+g
        int j = tid & 31;
        int t = combo >> 2, g = combo & 3;
        const float4* bp = (const float4*)(sp + (size_t)(t*16 + b*4 + g)*512 + j*16);
        float s = 0.f, ss = 0.f;
        #pragma unroll
        for (int k = 0; k < 4; ++k){ float4 v = bp[k]; s += v.x+v.z; ss += v.y+v.w; }
        s += __shfl_xor(s,1);  ss += __shfl_xor(ss,1);
        s += __shfl_xor(s,2);  ss += __shfl_xor(ss,2);
        s += __shfl_xor(s,4);  ss += __shfl_xor(ss,4);
        s += __shfl_xor(s,8);  ss += __shfl_xor(ss,8);
        s += __shfl_xor(s,16); ss += __shfl_xor(ss,16);
        if (j == 0){
            float m = s * (1.f/65536.f);
            float v = ss * (1.f/65536.f) - m*m;
            st[combo*2]   = m;
            st[combo*2+1] = rsqrtf(v + 1e-5f);
        }
    }
    const float* ysb = ys + ((size_t)(b*4096 + hw0))*64;
    const float* yeb = ye + ((size_t)(b*4096 + hw0))*64;
    #pragma unroll
    for (int it = 0; it < 8; ++it){
        int idx = it*256 + tid;
        tys[idx>>6][idx&63] = ysb[idx];
        tye[idx>>6][idx&63] = yeb[idx];
    }
    __syncthreads();
    float a0 = attw[0], a1 = attw[1];
    float mx = fmaxf(a0, a1);
    float e0 = __expf(a0-mx), e1 = __expf(a1-mx);
    float inv = 1.f/(e0+e1);
    float w0 = e0*inv, w1 = e1*inv;
    #pragma unroll
    for (int it = 0; it < 8; ++it){
        int idx = it*256 + tid;
        int c = idx >> 5, hwi = idx & 31;
        int g = c >> 4;
        size_t gx = ((size_t)(b*64 + c))*4096 + hw0 + hwi;
        float xv = x[gx];
        float ns = (tys[hwi][c] - st[g*2])     * st[g*2+1]     * gsw[c] + gsb[c];
        float ne = (tye[hwi][c] - st[8+g*2])   * st[8+g*2+1]   * gew[c] + geb[c];
        out[gx] = w0*(siluf(ns)+xv) + w1*(xv+siluf(ne)) + xv;
    }
}

// ---- workspace layout (floats) ------------------------------------------
#define OFF_YS 0u           // 1,048,576 (ys)
#define OFF_XC 1048832u     // 2,097,152
#define OFF_Z  3145984u     // 2,097,152
#define OFF_PB 5243136u     // 2,097,152 (1024 units x 2048)
#define OFF_QB 7340288u     // 2,097,152
#define OFF_HS 9437440u     // 2,097,152
#define OFF_YE 11534592u    // 1,048,576
#define OFF_PS 12583168u    // 32,768
#define OFF_QS 12615936u    // 32,768
#define OFF_SP 12648704u    // 16,384

extern "C" void kernel_launch(void* const* d_in, const int* in_sizes, int n_in,
                              void* d_out, int out_size, void* d_ws, size_t ws_size,
                              hipStream_t stream) {
    const float* x           = (const float*)d_in[0];
    const float* spa_in_w    = (const float*)d_in[1];
    const float* spa_conv_w  = (const float*)d_in[2];
    const float* spa_conv_b  = (const float*)d_in[3];
    const float* spa_xproj_w = (const float*)d_in[4];
    const float* spa_dt_w    = (const float*)d_in[5];
    const float* spa_dt_b    = (const float*)d_in[6];
    const float* spa_A_log   = (const float*)d_in[7];
    const float* spa_D       = (const float*)d_in[8];
    const float* spa_out_w   = (const float*)d_in[9];
    const float* spe_in_w    = (const float*)d_in[10];
    const float* spe_conv_w  = (const float*)d_in[11];
    const float* spe_conv_b  = (const float*)d_in[12];
    const float* spe_xproj_w = (const float*)d_in[13];
    const float* spe_dt_w    = (const float*)d_in[14];
    const float* spe_dt_b    = (const float*)d_in[15];
    const float* spe_A_log   = (const float*)d_in[16];
    const float* spe_D       = (const float*)d_in[17];
    const float* spe_out_w   = (const float*)d_in[18];
    const float* spa_gn_w    = (const float*)d_in[19];
    const float* spa_gn_b    = (const float*)d_in[20];
    const float* spe_gn_w    = (const float*)d_in[21];
    const float* spe_gn_b    = (const float*)d_in[22];
    const float* att_w       = (const float*)d_in[23];

    float* ws  = (float*)d_ws;
    float* xc  = ws + OFF_XC;
    float* zb  = ws + OFF_Z;
    float* Pb  = ws + OFF_PB;
    float* Qb  = ws + OFF_QB;
    float* Hs  = ws + OFF_HS;
    float* Ps  = ws + OFF_PS;
    float* Qs  = ws + OFF_QS;
    float* sp  = ws + OFF_SP;
    float* ysb = ws + OFF_YS;
    float* yeb = ws + OFF_YE;
    float* out = (float*)d_out;

    k_inproj_conv<<<2048, 256, 0, stream>>>(x, spa_in_w, spa_conv_w, spa_conv_b, xc, zb);
    k_scan_p1    <<<1024, 256, 0, stream>>>(xc, spa_xproj_w, spa_dt_w, spa_dt_b, spa_A_log,
                                            Pb, Qb);
    k_spe        <<<1024, 256, 0, stream>>>(x, spe_in_w, spe_conv_w, spe_conv_b, spe_xproj_w,
                                            spe_dt_w, spe_dt_b, spe_A_log, spe_D, spe_out_w,
                                            yeb, sp);
    k_scan_p2a   <<<128,  256, 0, stream>>>(Pb, Qb, Ps, Qs);
    k_scan_p2c   <<<128,  256, 0, stream>>>(Pb, Qb, Ps, Qs, Hs);
    k_scan_p3    <<<1024, 256, 0, stream>>>(xc, zb, spa_xproj_w, spa_dt_w, spa_dt_b,
                                            spa_A_log, spa_D, Hs, spa_out_w, ysb, sp);
    k_final      <<<512,  256, 0, stream>>>(x, ysb, yeb, sp, spa_gn_w, spa_gn_b,
                                            spe_gn_w, spe_gn_b, att_w, out);
}

// Round 13
// 114.895 us; speedup vs baseline: 6.0358x; 1.0305x over previous
//
#include <hip/hip_runtime.h>

__device__ __forceinline__ float siluf(float x){ return x / (1.f + __expf(-x)); }
__device__ __forceinline__ float softplusf(float x){
    return fmaxf(x, 0.f) + __logf(1.f + __expf(-fabsf(x)));
}
#if __has_builtin(__builtin_amdgcn_exp2f)
__device__ __forceinline__ float fexp2(float x){ return __builtin_amdgcn_exp2f(x); }
#else
__device__ __forceinline__ float fexp2(float x){ return exp2f(x); }
#endif

// ---- fused spa in_proj+conv+SiLU AND scan p1 (16-token chunks) -----------
// Phase 0 (x2 passes of 8 tokens): stage 11x64 x-tile, in_proj, conv ->
//   xc into LDS + HBM (for p3), z -> HBM. Identical math/order to R12.
// Phase 1: x_proj (dt+B) from LDS xc. Phase 2: P/Q chunk summary.
__global__ void __launch_bounds__(256) k_ip1(const float* __restrict__ x,
        const float* __restrict__ in_w, const float* __restrict__ cw, const float* __restrict__ cb,
        const float* __restrict__ xpw, const float* __restrict__ dtw, const float* __restrict__ dtb,
        const float* __restrict__ A_log,
        float* __restrict__ xc, float* __restrict__ zb,
        float* __restrict__ Pb, float* __restrict__ Qb){
    __shared__ float sxc[2048];
    __shared__ float sbm[256];
    __shared__ __align__(16) float dtr[64];
    __shared__ float sxe[11][68];
    const int tid = threadIdx.x;
    const int ch = blockIdx.x;           // 16-token chunk, 0..1023
    // ---- phase 0: in_proj + conv (2 passes of 8 tokens) ----
    {
        float wr[64];
        const float4* w4 = (const float4*)(in_w + tid*64);
        #pragma unroll
        for (int k = 0; k < 16; ++k){
            float4 v = w4[k];
            wr[4*k]=v.x; wr[4*k+1]=v.y; wr[4*k+2]=v.z; wr[4*k+3]=v.w;
        }
        float cw0=0.f,cw1=0.f,cw2=0.f,cw3=0.f,cbd=0.f;
        if (tid < 128){
            cw0 = cw[tid*4+0]; cw1 = cw[tid*4+1];
            cw2 = cw[tid*4+2]; cw3 = cw[tid*4+3];
            cbd = cb[tid];
        }
        for (int pass = 0; pass < 2; ++pass){
            int l0 = ch*16 + pass*8;
            #pragma unroll
            for (int it = 0; it < 3; ++it){
                int idx = it*256 + tid;
                if (idx < 704){
                    int r = idx >> 6, c = idx & 63;
                    int p = l0 - 3 + r;
                    float v = 0.f;
                    if (p >= 0) v = x[(size_t)(p >> 12)*262144 + c*4096 + (p & 4095)];
                    sxe[r][c] = v;
                }
            }
            __syncthreads();
            if (tid < 128){
                float acc[11];
                #pragma unroll
                for (int r = 0; r < 11; ++r) acc[r] = 0.f;
                #pragma unroll
                for (int k = 0; k < 16; ++k){
                    #pragma unroll
                    for (int r = 0; r < 11; ++r){
                        float4 v = *(const float4*)&sxe[r][4*k];
                        acc[r] = fmaf(v.x, wr[4*k],   acc[r]);
                        acc[r] = fmaf(v.y, wr[4*k+1], acc[r]);
                        acc[r] = fmaf(v.z, wr[4*k+2], acc[r]);
                        acc[r] = fmaf(v.w, wr[4*k+3], acc[r]);
                    }
                }
                #pragma unroll
                for (int r = 0; r < 8; ++r){
                    float a = fmaf(cw0, acc[r],   cbd);
                    a = fmaf(cw1, acc[r+1], a);
                    a = fmaf(cw2, acc[r+2], a);
                    a = fmaf(cw3, acc[r+3], a);
                    float v = siluf(a);
                    sxc[(pass*8+r)*128 + tid] = v;
                    xc[(size_t)(l0+r)*128 + tid] = v;
                }
            } else {
                float acc[8];
                #pragma unroll
                for (int r = 0; r < 8; ++r) acc[r] = 0.f;
                #pragma unroll
                for (int k = 0; k < 16; ++k){
                    #pragma unroll
                    for (int r = 0; r < 8; ++r){
                        float4 v = *(const float4*)&sxe[r+3][4*k];
                        acc[r] = fmaf(v.x, wr[4*k],   acc[r]);
                        acc[r] = fmaf(v.y, wr[4*k+1], acc[r]);
                        acc[r] = fmaf(v.z, wr[4*k+2], acc[r]);
                        acc[r] = fmaf(v.w, wr[4*k+3], acc[r]);
                    }
                }
                int dz = tid - 128;
                #pragma unroll
                for (int r = 0; r < 8; ++r) zb[(size_t)(l0+r)*128 + dz] = acc[r];
            }
            __syncthreads();
        }
    }
    // ---- phase 1: x_proj (dt + B) from LDS xc ----
    {
        int j = tid & 63, tg = tid >> 6;     // 4 token-groups x 4 tokens
        if (j < 20){
            const float4* w4  = (const float4*)(xpw + j*128);
            const float4* xc4 = (const float4*)sxc + tg*128;
            float acc[4];
            #pragma unroll
            for (int r = 0; r < 4; ++r) acc[r] = 0.f;
            #pragma unroll 8
            for (int k = 0; k < 32; ++k){
                float4 w = w4[k];
                #pragma unroll
                for (int r = 0; r < 4; ++r){
                    float4 v = xc4[r*32 + k];
                    acc[r] = fmaf(v.x, w.x, acc[r]);
                    acc[r] = fmaf(v.y, w.y, acc[r]);
                    acc[r] = fmaf(v.z, w.z, acc[r]);
                    acc[r] = fmaf(v.w, w.w, acc[r]);
                }
            }
            if (j < 4){
                #pragma unroll
                for (int r = 0; r < 4; ++r) dtr[(tg*4+r)*4 + j] = acc[r];
            } else {
                #pragma unroll
                for (int r = 0; r < 4; ++r) sbm[(tg*4+r)*16 + (j-4)] = acc[r];
            }
        }
    }
    __syncthreads();
    // ---- phase 2: P/Q chunk summary ----
    const int d  = tid & 127;
    const int sh = tid >> 7;
    float A8[8];
    {
        const float4* al4 = (const float4*)(A_log + d*16 + sh*8);
        float4 v0 = al4[0], v1 = al4[1];
        A8[0]=-__expf(v0.x)*1.44269504f; A8[1]=-__expf(v0.y)*1.44269504f;
        A8[2]=-__expf(v0.z)*1.44269504f; A8[3]=-__expf(v0.w)*1.44269504f;
        A8[4]=-__expf(v1.x)*1.44269504f; A8[5]=-__expf(v1.y)*1.44269504f;
        A8[6]=-__expf(v1.z)*1.44269504f; A8[7]=-__expf(v1.w)*1.44269504f;
    }
    float4 dw = *(const float4*)(dtw + d*4);
    float dbd = dtb[d];
    float P[8], Q[8];
    #pragma unroll
    for (int s = 0; s < 8; ++s){ P[s] = 1.f; Q[s] = 0.f; }
    #pragma unroll 4
    for (int i = 0; i < 16; ++i){
        float4 dt4 = *(const float4*)(dtr + i*4);
        float dv = dbd;
        dv = fmaf(dt4.x, dw.x, dv);
        dv = fmaf(dt4.y, dw.y, dv);
        dv = fmaf(dt4.z, dw.z, dv);
        dv = fmaf(dt4.w, dw.w, dv);
        float dt = softplusf(dv);
        float db = dt * sxc[i*128 + d];
        const float4* bmr = (const float4*)(sbm + i*16 + sh*8);
        float4 b0 = bmr[0], b1 = bmr[1];
        float bv[8] = {b0.x,b0.y,b0.z,b0.w,b1.x,b1.y,b1.z,b1.w};
        #pragma unroll
        for (int s = 0; s < 8; ++s){
            float a = fexp2(dt*A8[s]);
            P[s] *= a;
            Q[s] = fmaf(a, Q[s], db*bv[s]);
        }
    }
    float* Pp = Pb + (size_t)ch*2048 + d*16 + sh*8;
    float* Qp = Qb + (size_t)ch*2048 + d*16 + sh*8;
    ((float4*)Pp)[0] = make_float4(P[0],P[1],P[2],P[3]);
    ((float4*)Pp)[1] = make_float4(P[4],P[5],P[6],P[7]);
    ((float4*)Qp)[0] = make_float4(Q[0],Q[1],Q[2],Q[3]);
    ((float4*)Qp)[1] = make_float4(Q[4],Q[5],Q[6],Q[7]);
}

// ---- spe: per-pixel mamba; ALL per-lane weights staged to LDS ------------
#define XE_   0
#define XCL_  1216
#define BCL_  3904
#define DTV_  8640
#define SPG_  8768
#define WEIN_ 8800
#define WECW_ 9056
#define WECB_ 9120
#define WEAL_ 9136
#define WDTW_ 9392
#define WDTB_ 9408
#define WDV_  9424
__global__ void __launch_bounds__(256) k_spe(
        const float* __restrict__ x,
        const float* __restrict__ ein_w, const float* __restrict__ ecw, const float* __restrict__ ecb,
        const float* __restrict__ expw, const float* __restrict__ edtw, const float* __restrict__ edtb,
        const float* __restrict__ eA_log, const float* __restrict__ eDv, const float* __restrict__ eow,
        float* __restrict__ ye, float* __restrict__ sp)
{
    __shared__ float smem[9440];
    const int tid = threadIdx.x;
    const int pix = tid >> 4;
    const int d   = tid & 15;
    const int eb  = blockIdx.x;
    const int p0  = eb * 16;
    const int b   = p0 >> 12;
    const int hw0 = p0 & 4095;

    #pragma unroll
    for (int it = 0; it < 3; ++it){
        int idx = it*256 + tid;
        if (idx < 640){
            float v;
            if      (idx < 256) v = ein_w[idx];
            else if (idx < 320) v = ecw[idx-256];
            else if (idx < 336) v = ecb[idx-320];
            else if (idx < 592) v = eA_log[idx-336];
            else if (idx < 608) v = edtw[idx-592];
            else if (idx < 624) v = edtb[idx-608];
            else                v = eDv[idx-624];
            smem[WEIN_ + idx] = v;
        }
    }
    const float* xb = x + b*262144 + hw0;
    #pragma unroll
    for (int it = 0; it < 4; ++it){
        int idx = it*256 + tid;
        smem[XE_ + (idx&15)*76 + (idx>>4)] = xb[(idx>>4)*4096 + (idx&15)];
    }
    __syncthreads();

    float wi[8], wz[8];
    #pragma unroll
    for (int g = 0; g < 8; ++g){ wi[g] = smem[WEIN_ + d*8+g]; wz[g] = smem[WEIN_ + 128 + d*8+g]; }
    float xi[8], zz[8];
    {
        const float4* xe4 = (const float4*)(smem + XE_ + pix*76);
        #pragma unroll
        for (int t = 0; t < 8; ++t){
            float4 a = xe4[t*2], bq = xe4[t*2+1];
            float xv8[8] = {a.x,a.y,a.z,a.w,bq.x,bq.y,bq.z,bq.w};
            float ai = 0.f, az = 0.f;
            #pragma unroll
            for (int g = 0; g < 8; ++g){
                ai = fmaf(xv8[g], wi[g], ai);
                az = fmaf(xv8[g], wz[g], az);
            }
            xi[t] = ai; zz[t] = az;
        }
    }
    float c0 = smem[WECW_ + d*4+0], c1 = smem[WECW_ + d*4+1];
    float c2 = smem[WECW_ + d*4+2], c3 = smem[WECW_ + d*4+3];
    float cbd = smem[WECB_ + d];
    float xcr[8];
    #pragma unroll
    for (int t = 0; t < 8; ++t){
        float a = fmaf(c3, xi[t], cbd);
        if (t >= 1) a = fmaf(c2, xi[t-1], a);
        if (t >= 2) a = fmaf(c1, xi[t-2], a);
        if (t >= 3) a = fmaf(c0, xi[t-3], a);
        xcr[t] = siluf(a);
        smem[XCL_ + pix*168 + t*20 + d] = xcr[t];
    }
    __syncthreads();

    {
        const int row = tid & 127;
        const int jh  = tid >> 7;
        const int px2 = row >> 3;
        const int t2  = row & 7;
        const float4* xr = (const float4*)(smem + XCL_ + px2*168 + t2*20);
        float4 r0 = xr[0], r1 = xr[1], r2 = xr[2], r3 = xr[3];
        float xv[16] = {r0.x,r0.y,r0.z,r0.w, r1.x,r1.y,r1.z,r1.w,
                        r2.x,r2.y,r2.z,r2.w, r3.x,r3.y,r3.z,r3.w};
        const float* wbase = expw + (1 + jh*16)*16;
        float outv[16];
        #pragma unroll
        for (int s = 0; s < 16; ++s){
            const float* wr = wbase + s*16;
            float a = 0.f;
            #pragma unroll
            for (int k = 0; k < 16; ++k) a = fmaf(xv[k], wr[k], a);
            outv[s] = a;
        }
        float4* dst4 = (float4*)(smem + BCL_ + px2*296 + t2*36 + jh*16);
        dst4[0] = make_float4(outv[0], outv[1], outv[2], outv[3]);
        dst4[1] = make_float4(outv[4], outv[5], outv[6], outv[7]);
        dst4[2] = make_float4(outv[8], outv[9], outv[10],outv[11]);
        dst4[3] = make_float4(outv[12],outv[13],outv[14],outv[15]);
        if (jh == 0){
            float accd = 0.f;
            #pragma unroll
            for (int k = 0; k < 16; ++k) accd = fmaf(xv[k], expw[k], accd);
            smem[DTV_ + px2*8 + t2] = accd;
        }
    }
    __syncthreads();

    float A16[16];
    #pragma unroll
    for (int s = 0; s < 16; ++s) A16[s] = -__expf(smem[WEAL_ + d*16+s]) * 1.44269504f;
    float dwd = smem[WDTW_ + d], dbd = smem[WDTB_ + d], Dd = smem[WDV_ + d];
    float h[16];
    #pragma unroll
    for (int s = 0; s < 16; ++s) h[s] = 0.f;
    #pragma unroll
    for (int t = 0; t < 8; ++t){
        float dtd = softplusf(fmaf(smem[DTV_ + pix*8 + t], dwd, dbd));
        float db = dtd * xcr[t];
        const float4* bc4 = (const float4*)(smem + BCL_ + pix*296 + t*36);
        float4 b0 = bc4[0], b1 = bc4[1], b2 = bc4[2], b3 = bc4[3];
        float4 cc0 = bc4[4], cc1 = bc4[5], cc2 = bc4[6], cc3 = bc4[7];
        float bv[16] = {b0.x,b0.y,b0.z,b0.w, b1.x,b1.y,b1.z,b1.w,
                        b2.x,b2.y,b2.z,b2.w, b3.x,b3.y,b3.z,b3.w};
        float cv[16] = {cc0.x,cc0.y,cc0.z,cc0.w, cc1.x,cc1.y,cc1.z,cc1.w,
                        cc2.x,cc2.y,cc2.z,cc2.w, cc3.x,cc3.y,cc3.z,cc3.w};
        float yp = 0.f;
        #pragma unroll
        for (int s = 0; s < 16; ++s){
            float a = fexp2(dtd*A16[s]);
            h[s] = fmaf(a, h[s], db*bv[s]);
            yp = fmaf(h[s], cv[s], yp);
        }
        smem[pix*168 + t*20 + d] = (yp + xcr[t]*Dd) * siluf(zz[t]);
    }
    __syncthreads();

    {
        const int half = tid >> 7;
        const int idx7 = tid & 127;
        const int pixD = idx7 >> 3;
        const int ttD  = idx7 & 7;
        const int m0   = half*4;
        const float4* y4 = (const float4*)(smem + pixD*168 + ttD*20);
        float4 y0 = y4[0], y1 = y4[1], y2 = y4[2], y3 = y4[3];
        float ylr[16] = {y0.x,y0.y,y0.z,y0.w, y1.x,y1.y,y1.z,y1.w,
                         y2.x,y2.y,y2.z,y2.w, y3.x,y3.y,y3.z,y3.w};
        float acc[4];
        #pragma unroll
        for (int mm = 0; mm < 4; ++mm){
            const float* wr = eow + (m0+mm)*16;
            float a = 0.f;
            #pragma unroll
            for (int k = 0; k < 16; ++k) a = fmaf(ylr[k], wr[k], a);
            acc[mm] = a;
        }
        float4 o; o.x=acc[0]; o.y=acc[1]; o.z=acc[2]; o.w=acc[3];
        *(float4*)(ye + (size_t)(p0+pixD)*64 + ttD*8 + m0) = o;

        float s  = acc[0]+acc[1]+acc[2]+acc[3];
        float ss = acc[0]*acc[0]+acc[1]*acc[1]+acc[2]*acc[2]+acc[3]*acc[3];
        s += __shfl_xor(s,1);  ss += __shfl_xor(ss,1);
        s += __shfl_xor(s,8);  ss += __shfl_xor(ss,8);
        s += __shfl_xor(s,16); ss += __shfl_xor(ss,16);
        s += __shfl_xor(s,32); ss += __shfl_xor(ss,32);
        int lane = tid & 63, wv = tid >> 6;
        if ((lane & 57) == 0){
            smem[SPG_ + wv*4 + ((lane>>1)&3)] = s;
            smem[SPG_ + 16 + wv*4 + ((lane>>1)&3)] = ss;
        }
    }
    __syncthreads();
    if (tid < 4){
        int blk = eb & 255;
        float S  = smem[SPG_+0*4+tid]+smem[SPG_+1*4+tid]+smem[SPG_+2*4+tid]+smem[SPG_+3*4+tid];
        float SS = smem[SPG_+16+0*4+tid]+smem[SPG_+16+1*4+tid]+smem[SPG_+16+2*4+tid]+smem[SPG_+16+3*4+tid];
        float* dst = sp + (size_t)(((4 + b)*4 + tid)*512 + blk*2);
        dst[0] = S; dst[1] = SS;
    }
}

// ---- scan pass 2a: compose 64 half-chunk units per super (16 supers) -----
__global__ void __launch_bounds__(256) k_scan_p2a(const float* __restrict__ Pb,
        const float* __restrict__ Qb, float* __restrict__ Ps, float* __restrict__ Qs){
    int g = blockIdx.x*256 + threadIdx.x;   // 0..32767
    int sup = g >> 11;
    int lane = g & 2047;
    float P = 1.f, Q = 0.f;
    for (int i = 0; i < 64; i += 8){
        float p[8], q[8];
        #pragma unroll
        for (int u = 0; u < 8; ++u){
            p[u] = Pb[(size_t)(sup*64+i+u)*2048 + lane];
            q[u] = Qb[(size_t)(sup*64+i+u)*2048 + lane];
        }
        #pragma unroll
        for (int u = 0; u < 8; ++u){
            P = p[u]*P;
            Q = fmaf(p[u], Q, q[u]);
        }
    }
    Ps[g] = P; Qs[g] = Q;
}

// ---- scan pass 2c: unit-level prefix (1024 units); Hsup inline -----------
__global__ void __launch_bounds__(256) k_scan_p2c(const float* __restrict__ Pb,
        const float* __restrict__ Qb, const float* __restrict__ Ps,
        const float* __restrict__ Qs, float* __restrict__ Hs){
    int g = blockIdx.x*256 + threadIdx.x;
    int sup = g >> 11;                 // block-uniform
    int lane = g & 2047;
    float h = 0.f;
    for (int u = 0; u < sup; ++u){
        float p = Ps[u*2048 + lane];
        float q = Qs[u*2048 + lane];
        h = fmaf(p, h, q);
    }
    for (int i = 0; i < 64; i += 8){
        float p[8], q[8];
        #pragma unroll
        for (int u = 0; u < 8; ++u){
            p[u] = Pb[(size_t)(sup*64+i+u)*2048 + lane];
            q[u] = Qb[(size_t)(sup*64+i+u)*2048 + lane];
        }
        #pragma unroll
        for (int u = 0; u < 8; ++u){
            Hs[(size_t)(sup*64+i+u)*2048 + lane] = h;
            h = fmaf(p[u], h, q[u]);
        }
    }
}

// ---- spa scan pass 3: 16-token chunks (1024 blocks), h0 from Hs, fused
//      x_proj (dt+B+C), gate, D-skip, out_proj + GN partials ---------------
__global__ void __launch_bounds__(256) k_scan_p3(const float* __restrict__ xc,
        const float* __restrict__ zb, const float* __restrict__ xpw, const float* __restrict__ dtw,
        const float* __restrict__ dtb, const float* __restrict__ A_log, const float* __restrict__ Dv,
        const float* __restrict__ Hs, const float* __restrict__ ow,
        float* __restrict__ ys, float* __restrict__ sp){
    __shared__ float sxc[16*128];
    __shared__ float ypl[2][16*128];
    __shared__ float sbm[16*16];
    __shared__ float scm[16*16];
    __shared__ __align__(16) float dtr[16][4];
    __shared__ float pgs[2][2][4];
    const int tid = threadIdx.x;
    const int ch = blockIdx.x;            // 0..1023
    {
        const float4* src = (const float4*)(xc + (size_t)ch*2048);
        float4* dst = (float4*)sxc;
        dst[tid] = src[tid];
        dst[256 + tid] = src[256 + tid];
    }
    __syncthreads();
    {
        int j = tid & 63, tg = tid >> 6;
        if (j < 36){
            const float4* w4  = (const float4*)(xpw + j*128);
            const float4* xc4 = (const float4*)sxc + tg*128;   // 4 tokens x 32 f4
            float acc[4];
            #pragma unroll
            for (int r = 0; r < 4; ++r) acc[r] = 0.f;
            #pragma unroll 8
            for (int k = 0; k < 32; ++k){
                float4 w = w4[k];
                #pragma unroll
                for (int r = 0; r < 4; ++r){
                    float4 v = xc4[r*32 + k];
                    acc[r] = fmaf(v.x, w.x, acc[r]);
                    acc[r] = fmaf(v.y, w.y, acc[r]);
                    acc[r] = fmaf(v.z, w.z, acc[r]);
                    acc[r] = fmaf(v.w, w.w, acc[r]);
                }
            }
            if (j < 4){
                #pragma unroll
                for (int r = 0; r < 4; ++r) dtr[tg*4+r][j] = acc[r];
            } else if (j < 20){
                #pragma unroll
                for (int r = 0; r < 4; ++r) sbm[(tg*4+r)*16 + (j-4)] = acc[r];
            } else {
                #pragma unroll
                for (int r = 0; r < 4; ++r) scm[(tg*4+r)*16 + (j-20)] = acc[r];
            }
        }
    }
    __syncthreads();
    const int d  = tid & 127;
    const int sh = tid >> 7;
    float A8[8], h[8];
    {
        const float4* al4 = (const float4*)(A_log + d*16 + sh*8);
        float4 v0 = al4[0], v1 = al4[1];
        A8[0]=-__expf(v0.x)*1.44269504f; A8[1]=-__expf(v0.y)*1.44269504f;
        A8[2]=-__expf(v0.z)*1.44269504f; A8[3]=-__expf(v0.w)*1.44269504f;
        A8[4]=-__expf(v1.x)*1.44269504f; A8[5]=-__expf(v1.y)*1.44269504f;
        A8[6]=-__expf(v1.z)*1.44269504f; A8[7]=-__expf(v1.w)*1.44269504f;
        const float4* h4 = (const float4*)(Hs + (size_t)ch*2048 + d*16 + sh*8);
        float4 h0 = h4[0], h1 = h4[1];
        h[0]=h0.x; h[1]=h0.y; h[2]=h0.z; h[3]=h0.w;
        h[4]=h1.x; h[5]=h1.y; h[6]=h1.z; h[7]=h1.w;
    }
    float4 dw = *(const float4*)(dtw + d*4);
    float dbd = dtb[d];
    #pragma unroll 4
    for (int i = 0; i < 16; ++i){
        float4 dt4 = *(const float4*)dtr[i];
        float dv = dbd;
        dv = fmaf(dt4.x, dw.x, dv);
        dv = fmaf(dt4.y, dw.y, dv);
        dv = fmaf(dt4.z, dw.z, dv);
        dv = fmaf(dt4.w, dw.w, dv);
        float dt = softplusf(dv);
        float db = dt * sxc[i*128 + d];
        const float4* bmr = (const float4*)(sbm + i*16 + sh*8);
        const float4* cmr = (const float4*)(scm + i*16 + sh*8);
        float4 b0 = bmr[0], b1 = bmr[1];
        float4 c0 = cmr[0], c1 = cmr[1];
        float bv[8] = {b0.x,b0.y,b0.z,b0.w,b1.x,b1.y,b1.z,b1.w};
        float cv[8] = {c0.x,c0.y,c0.z,c0.w,c1.x,c1.y,c1.z,c1.w};
        float yp = 0.f;
        #pragma unroll
        for (int s = 0; s < 8; ++s){
            float a = fexp2(dt*A8[s]);
            h[s] = fmaf(a, h[s], db*bv[s]);
            yp = fmaf(h[s], cv[s], yp);
        }
        ypl[sh][i*128 + d] = yp;
    }
    __syncthreads();
    #pragma unroll
    for (int it = 0; it < 8; ++it){
        int idx = it*256 + tid;
        float yp = ypl[0][idx] + ypl[1][idx];
        float xcd = sxc[idx];
        float zv = zb[(size_t)ch*2048 + idx];
        ypl[0][idx] = (yp + xcd*Dv[idx & 127]) * siluf(zv);
    }
    __syncthreads();
    // out_proj: [16 x 128] @ [128 -> 64], k-split 2, partials via ypl[1]
    {
        int c  = tid & 63;
        int kh = (tid >> 6) & 1;
        int rg = tid >> 7;                // 2 row groups x 8 rows
        float wr[64];
        const float4* w4o = (const float4*)(ow + c*128 + kh*64);
        #pragma unroll
        for (int k = 0; k < 16; ++k){
            float4 v = w4o[k];
            wr[4*k]=v.x; wr[4*k+1]=v.y; wr[4*k+2]=v.z; wr[4*k+3]=v.w;
        }
        float acc[8];
        #pragma unroll
        for (int r = 0; r < 8; ++r) acc[r] = 0.f;
        const float4* y4 = (const float4*)(ypl[0] + rg*8*128 + kh*64);
        #pragma unroll
        for (int k = 0; k < 16; ++k){
            #pragma unroll
            for (int r = 0; r < 8; ++r){
                float4 v = y4[r*32 + k];
                acc[r] = fmaf(v.x, wr[4*k],   acc[r]);
                acc[r] = fmaf(v.y, wr[4*k+1], acc[r]);
                acc[r] = fmaf(v.z, wr[4*k+2], acc[r]);
                acc[r] = fmaf(v.w, wr[4*k+3], acc[r]);
            }
        }
        float* part = ypl[1];
        if (kh == 1){
            #pragma unroll
            for (int r = 0; r < 8; ++r) part[(rg*8+r)*64 + c] = acc[r];
        }
        __syncthreads();
        if (kh == 0){
            float s = 0.f, ss = 0.f;
            #pragma unroll
            for (int r = 0; r < 8; ++r){
                float v = acc[r] + part[(rg*8+r)*64 + c];
                ys[(size_t)(ch*16 + rg*8 + r)*64 + c] = v;
                s += v; ss += v*v;
            }
            s += __shfl_xor(s,1); ss += __shfl_xor(ss,1);
            s += __shfl_xor(s,2); ss += __shfl_xor(ss,2);
            s += __shfl_xor(s,4); ss += __shfl_xor(ss,4);
            s += __shfl_xor(s,8); ss += __shfl_xor(ss,8);
            if ((c & 15) == 0){ pgs[0][rg][c>>4] = s; pgs[1][rg][c>>4] = ss; }
        }
        __syncthreads();
        if (tid < 4){
            int b = ch >> 8, blk = ch & 255;
            float S  = pgs[0][0][tid] + pgs[0][1][tid];
            float SS = pgs[1][0][tid] + pgs[1][1][tid];
            float* dst = sp + (size_t)((b*4 + tid)*512 + blk*2);
            dst[0] = S; dst[1] = SS;
        }
    }
}

// ---- final: reduce GN partials (256 slices each), normalize, combine -----
__global__ void __launch_bounds__(256) k_final(const float* __restrict__ x,
        const float* __restrict__ ys, const float* __restrict__ ye,
        const float* __restrict__ sp,
        const float* __restrict__ gsw, const float* __restrict__ gsb,
        const float* __restrict__ gew, const float* __restrict__ geb,
        const float* __restrict__ attw, float* __restrict__ out){
    __shared__ float st[16];         // 8 combos (t*4+g) x {mean, rstd}
    __shared__ float tys[32][65];
    __shared__ float tye[32][65];
    int tid = threadIdx.x;
    int b   = blockIdx.x >> 7;
    int hw0 = (blockIdx.x & 127) << 5;
    {
        int combo = tid >> 5;        // t*4+g
        int j = tid & 31;
        int t = combo >> 2, g = combo & 3;
        const float4* bp = (const float4*)(sp + (size_t)(t*16 + b*4 + g)*512 + j*16);
        float s = 0.f, ss = 0.f;
        #pragma unroll
        for (int k = 0; k < 4; ++k){ float4 v = bp[k]; s += v.x+v.z; ss += v.y+v.w; }
        s += __shfl_xor(s,1);  ss += __shfl_xor(ss,1);
        s += __shfl_xor(s,2);  ss += __shfl_xor(ss,2);
        s += __shfl_xor(s,4);  ss += __shfl_xor(ss,4);
        s += __shfl_xor(s,8);  ss += __shfl_xor(ss,8);
        s += __shfl_xor(s,16); ss += __shfl_xor(ss,16);
        if (j == 0){
            float m = s * (1.f/65536.f);
            float v = ss * (1.f/65536.f) - m*m;
            st[combo*2]   = m;
            st[combo*2+1] = rsqrtf(v + 1e-5f);
        }
    }
    const float* ysb = ys + ((size_t)(b*4096 + hw0))*64;
    const float* yeb = ye + ((size_t)(b*4096 + hw0))*64;
    #pragma unroll
    for (int it = 0; it < 8; ++it){
        int idx = it*256 + tid;
        tys[idx>>6][idx&63] = ysb[idx];
        tye[idx>>6][idx&63] = yeb[idx];
    }
    __syncthreads();
    float a0 = attw[0], a1 = attw[1];
    float mx = fmaxf(a0, a1);
    float e0 = __expf(a0-mx), e1 = __expf(a1-mx);
    float inv = 1.f/(e0+e1);
    float w0 = e0*inv, w1 = e1*inv;
    #pragma unroll
    for (int it = 0; it < 8; ++it){
        int idx = it*256 + tid;
        int c = idx >> 5, hwi = idx & 31;
        int g = c >> 4;
        size_t gx = ((size_t)(b*64 + c))*4096 + hw0 + hwi;
        float xv = x[gx];
        float ns = (tys[hwi][c] - st[g*2])     * st[g*2+1]     * gsw[c] + gsb[c];
        float ne = (tye[hwi][c] - st[8+g*2])   * st[8+g*2+1]   * gew[c] + geb[c];
        out[gx] = w0*(siluf(ns)+xv) + w1*(xv+siluf(ne)) + xv;
    }
}

// ---- workspace layout (floats) ------------------------------------------
#define OFF_YS 0u           // 1,048,576 (ys)
#define OFF_XC 1048832u     // 2,097,152
#define OFF_Z  3145984u     // 2,097,152
#define OFF_PB 5243136u     // 2,097,152 (1024 units x 2048)
#define OFF_QB 7340288u     // 2,097,152
#define OFF_HS 9437440u     // 2,097,152
#define OFF_YE 11534592u    // 1,048,576
#define OFF_PS 12583168u    // 32,768
#define OFF_QS 12615936u    // 32,768
#define OFF_SP 12648704u    // 16,384

extern "C" void kernel_launch(void* const* d_in, const int* in_sizes, int n_in,
                              void* d_out, int out_size, void* d_ws, size_t ws_size,
                              hipStream_t stream) {
    const float* x           = (const float*)d_in[0];
    const float* spa_in_w    = (const float*)d_in[1];
    const float* spa_conv_w  = (const float*)d_in[2];
    const float* spa_conv_b  = (const float*)d_in[3];
    const float* spa_xproj_w = (const float*)d_in[4];
    const float* spa_dt_w    = (const float*)d_in[5];
    const float* spa_dt_b    = (const float*)d_in[6];
    const float* spa_A_log   = (const float*)d_in[7];
    const float* spa_D       = (const float*)d_in[8];
    const float* spa_out_w   = (const float*)d_in[9];
    const float* spe_in_w    = (const float*)d_in[10];
    const float* spe_conv_w  = (const float*)d_in[11];
    const float* spe_conv_b  = (const float*)d_in[12];
    const float* spe_xproj_w = (const float*)d_in[13];
    const float* spe_dt_w    = (const float*)d_in[14];
    const float* spe_dt_b    = (const float*)d_in[15];
    const float* spe_A_log   = (const float*)d_in[16];
    const float* spe_D       = (const float*)d_in[17];
    const float* spe_out_w   = (const float*)d_in[18];
    const float* spa_gn_w    = (const float*)d_in[19];
    const float* spa_gn_b    = (const float*)d_in[20];
    const float* spe_gn_w    = (const float*)d_in[21];
    const float* spe_gn_b    = (const float*)d_in[22];
    const float* att_w       = (const float*)d_in[23];

    float* ws  = (float*)d_ws;
    float* xc  = ws + OFF_XC;
    float* zb  = ws + OFF_Z;
    float* Pb  = ws + OFF_PB;
    float* Qb  = ws + OFF_QB;
    float* Hs  = ws + OFF_HS;
    float* Ps  = ws + OFF_PS;
    float* Qs  = ws + OFF_QS;
    float* sp  = ws + OFF_SP;
    float* ysb = ws + OFF_YS;
    float* yeb = ws + OFF_YE;
    float* out = (float*)d_out;

    k_ip1     <<<1024, 256, 0, stream>>>(x, spa_in_w, spa_conv_w, spa_conv_b,
                                         spa_xproj_w, spa_dt_w, spa_dt_b, spa_A_log,
                                         xc, zb, Pb, Qb);
    k_spe     <<<1024, 256, 0, stream>>>(x, spe_in_w, spe_conv_w, spe_conv_b, spe_xproj_w,
                                         spe_dt_w, spe_dt_b, spe_A_log, spe_D, spe_out_w,
                                         yeb, sp);
    k_scan_p2a<<<128,  256, 0, stream>>>(Pb, Qb, Ps, Qs);
    k_scan_p2c<<<128,  256, 0, stream>>>(Pb, Qb, Ps, Qs, Hs);
    k_scan_p3 <<<1024, 256, 0, stream>>>(xc, zb, spa_xproj_w, spa_dt_w, spa_dt_b,
                                         spa_A_log, spa_D, Hs, spa_out_w, ysb, sp);
    k_final   <<<512,  256, 0, stream>>>(x, ysb, yeb, sp, spa_gn_w, spa_gn_b,
                                         spe_gn_w, spe_gn_b, att_w, out);
}